// Round 2
// baseline (28936.371 us; speedup 1.0000x reference)
//
#include <hip/hip_runtime.h>
#include <math.h>

#define NDIMX 2941
#define NQ 1200
#define KB 800
#define KP 720
#define KU 1520
#define NC 400
#define NBATCH 128
#define NRHS 528

__device__ __forceinline__ int umap(int x){ return (x < 1200) ? x : x - 720; }

__device__ __forceinline__ const float* qrowp(int rr, const float* Yf, const float* Uf,
                                              const float* Up, const float* Yp){
  if (rr < 480) return Yf + (size_t)rr*NDIMX;
  if (rr < 800) return Uf + (size_t)(rr-480)*NDIMX;
  if (rr < 960) return Up + (size_t)(rr-800)*NDIMX;
  return Yp + (size_t)(rr-960)*NDIMX;
}

// ---------------- Gram kernel: 64x64 tile, 4x4/thread, f32 acc, f64 store ----------------
__global__ __launch_bounds__(256) void k_gram(const float* __restrict__ Yf, const float* __restrict__ Uf,
    const float* __restrict__ Up, const float* __restrict__ Yp, double* __restrict__ G){
  int rem = blockIdx.x, ti = 0;
  while (rem >= ti+1){ rem -= ti+1; ++ti; }
  int tj = rem;
  __shared__ float At[32][65];
  __shared__ float Bt[32][65];
  int tid = threadIdx.x, tx = tid%16, ty = tid/16;
  float acc[4][4] = {};
  int i0 = ti*64, j0 = tj*64;
  for (int k0 = 0; k0 < NDIMX; k0 += 32){
    for (int l = tid; l < 2048; l += 256){
      int r2 = l >> 5, k = l & 31;
      int gr = i0 + r2, gk = k0 + k;
      At[k][r2] = (gr < NQ && gk < NDIMX) ? qrowp(gr,Yf,Uf,Up,Yp)[gk] : 0.f;
    }
    if (ti != tj){
      for (int l = tid; l < 2048; l += 256){
        int r2 = l >> 5, k = l & 31;
        int gr = j0 + r2, gk = k0 + k;
        Bt[k][r2] = (gr < NQ && gk < NDIMX) ? qrowp(gr,Yf,Uf,Up,Yp)[gk] : 0.f;
      }
    }
    __syncthreads();
    float (*Bp)[65] = (ti==tj) ? At : Bt;
    #pragma unroll 8
    for (int kk=0; kk<32; ++kk){
      float a0=At[kk][ty*4+0],a1=At[kk][ty*4+1],a2=At[kk][ty*4+2],a3=At[kk][ty*4+3];
      float b0=Bp[kk][tx*4+0],b1=Bp[kk][tx*4+1],b2=Bp[kk][tx*4+2],b3=Bp[kk][tx*4+3];
      acc[0][0]+=a0*b0; acc[0][1]+=a0*b1; acc[0][2]+=a0*b2; acc[0][3]+=a0*b3;
      acc[1][0]+=a1*b0; acc[1][1]+=a1*b1; acc[1][2]+=a1*b2; acc[1][3]+=a1*b3;
      acc[2][0]+=a2*b0; acc[2][1]+=a2*b1; acc[2][2]+=a2*b2; acc[2][3]+=a2*b3;
      acc[3][0]+=a3*b0; acc[3][1]+=a3*b1; acc[3][2]+=a3*b2; acc[3][3]+=a3*b3;
    }
    __syncthreads();
  }
  for (int i=0;i<4;i++) for (int j=0;j<4;j++){
    int gi = i0 + ty*4 + i, gj = j0 + tx*4 + j;
    if (gi < NQ && gj < NQ){
      double v = (double)acc[i][j];
      G[(size_t)gi*NQ+gj] = v;
      G[(size_t)gj*NQ+gi] = v;
    }
  }
}

// ---------------- small helper kernels ----------------
__global__ void k_consts(const float* __restrict__ lam, double* __restrict__ c){
  if (threadIdx.x==0 && blockIdx.x==0){
    double sg = 2.0*(double)lam[0];
    c[0]=1.0; c[1]=0.0; c[2]=-1.0; c[3]=sg;
    c[4]=1.0/sg; c[5]=-1.0/sg; c[6]=1.0/(sg*sg); c[7]=-1.0/(sg*sg);
  }
}

__global__ __launch_bounds__(256) void k_asm_M11(const double* __restrict__ G, const float* __restrict__ q,
    const float* __restrict__ r, const double* __restrict__ cst, double* __restrict__ M11){
  int idx = blockIdx.x*256 + threadIdx.x;
  if (idx >= KB*KB) return;
  int i = idx / KB, j = idx % KB;
  double v = G[(size_t)i*NQ + j]*cst[4];
  if (i == j){
    double w = (i<480) ? (double)q[i%12] : (double)r[(i-480)%8];
    v += 0.5/w;
  }
  M11[idx] = v;
}

__global__ __launch_bounds__(256) void k_asm_M12(const double* __restrict__ G, const double* __restrict__ cst,
    double* __restrict__ M12){
  int idx = blockIdx.x*256 + threadIdx.x;
  if (idx >= KB*KP) return;
  int i = idx / KP, j = idx % KP;
  int pc = (j < 400) ? (800 + j) : (80 + j);
  M12[idx] = G[(size_t)i*NQ + pc]*cst[4];
}

__global__ __launch_bounds__(256) void k_asm_R1J(const double* __restrict__ G, double* __restrict__ R1){
  int idx = blockIdx.x*256 + threadIdx.x;
  if (idx >= KU*NC) return;
  int i = idx / NC, j = idx % NC;
  R1[(size_t)i*NRHS + j] = G[(size_t)umap(i)*NQ + 800 + j];
}

__global__ __launch_bounds__(256) void k_build_d(const float* __restrict__ q, const float* __restrict__ r,
    const float* __restrict__ yref, const float* __restrict__ uref, double* __restrict__ dM){
  int idx = blockIdx.x*256 + threadIdx.x;
  if (idx >= KB*NBATCH) return;
  int k = idx / NBATCH, t = idx % NBATCH;
  double v;
  if (k < 480) v = 2.0*(double)q[k%12]*(double)yref[(size_t)t*480 + k];
  else         v = 2.0*(double)r[(k-480)%8]*(double)uref[(size_t)t*320 + (k-480)];
  dM[idx] = v;
}

__global__ __launch_bounds__(256) void k_build_negb(const float* __restrict__ u_ini,
    const float* __restrict__ y_ini, double* __restrict__ nb){
  int idx = blockIdx.x*256 + threadIdx.x;
  if (idx >= NC*NBATCH) return;
  int j = idx / NBATCH, t = idx % NBATCH;
  double v = (j < 160) ? (double)u_ini[(size_t)t*160 + j] : (double)y_ini[(size_t)t*240 + (j-160)];
  nb[idx] = -v;
}

__global__ __launch_bounds__(256) void k_dcopy(const double* __restrict__ s, double* __restrict__ d, int n){
  int i = blockIdx.x*256 + threadIdx.x;
  if (i < n) d[i] = s[i];
}

__global__ __launch_bounds__(256) void k_out(const double* __restrict__ Bg, float* __restrict__ out){
  int idx = blockIdx.x*256 + threadIdx.x;
  if (idx < 128*320){
    int t = idx/320, i = idx%320;
    out[idx] = (float)Bg[(size_t)(480+i)*NBATCH + t];
  } else if (idx < 128*320 + 128*480){
    int l = idx - 128*320;
    int t = l/480, i = l%480;
    out[idx] = (float)Bg[(size_t)i*NBATCH + t];
  }
}

// ---------------- generic f64 GEMM: Cout = alpha*op(A)@B + beta*Cin ----------------
// MAPA: row index of A (storage row) goes through umap() and lda must be NQ (Gram view).
template<int TRANSA, int MAPA>
__global__ __launch_bounds__(256) void k_gemm(const double* __restrict__ A, int lda,
    const double* __restrict__ B, int ldb, const double* __restrict__ Cin, int ldcin,
    double* __restrict__ Cout, int ldc, int M, int N, int K,
    const double* __restrict__ alphaP, const double* __restrict__ betaP){
  __shared__ double As[16][66];
  __shared__ double Bs[16][66];
  int tid = threadIdx.x, tx = tid%16, ty = tid/16;
  int m0 = blockIdx.y*64, n0 = blockIdx.x*64;
  double acc[4][4] = {};
  for (int k0 = 0; k0 < K; k0 += 16){
    if (TRANSA == 0){
      for (int l = tid; l < 1024; l += 256){
        int m = l/16, k = l%16;
        int gm = m0+m, gk = k0+k;
        double v = 0.0;
        if (gm<M && gk<K){
          int row = MAPA ? umap(gm) : gm;
          v = A[(size_t)row*lda + gk];
        }
        As[k][m] = v;
      }
    } else {
      for (int l = tid; l < 1024; l += 256){
        int k = l/64, m = l%64;
        int gm = m0+m, gk = k0+k;
        double v = 0.0;
        if (gm<M && gk<K){
          int row = MAPA ? umap(gk) : gk;
          v = A[(size_t)row*lda + gm];
        }
        As[k][m] = v;
      }
    }
    for (int l = tid; l < 1024; l += 256){
      int k = l/64, n = l%64;
      int gn = n0+n, gk = k0+k;
      Bs[k][n] = (gn<N && gk<K) ? B[(size_t)gk*ldb + gn] : 0.0;
    }
    __syncthreads();
    #pragma unroll
    for (int kk=0; kk<16; ++kk){
      double a0=As[kk][ty*4+0], a1=As[kk][ty*4+1], a2=As[kk][ty*4+2], a3=As[kk][ty*4+3];
      double b0=Bs[kk][tx*4+0], b1=Bs[kk][tx*4+1], b2=Bs[kk][tx*4+2], b3=Bs[kk][tx*4+3];
      acc[0][0]+=a0*b0; acc[0][1]+=a0*b1; acc[0][2]+=a0*b2; acc[0][3]+=a0*b3;
      acc[1][0]+=a1*b0; acc[1][1]+=a1*b1; acc[1][2]+=a1*b2; acc[1][3]+=a1*b3;
      acc[2][0]+=a2*b0; acc[2][1]+=a2*b1; acc[2][2]+=a2*b2; acc[2][3]+=a2*b3;
      acc[3][0]+=a3*b0; acc[3][1]+=a3*b1; acc[3][2]+=a3*b2; acc[3][3]+=a3*b3;
    }
    __syncthreads();
  }
  double alpha = *alphaP, beta = *betaP;
  for (int i=0;i<4;i++) for (int j=0;j<4;j++){
    int gm = m0 + ty*4 + i, gn = n0 + tx*4 + j;
    if (gm < M && gn < N){
      double v = alpha*acc[i][j];
      if (beta != 0.0) v += beta*Cin[(size_t)gm*ldcin + gn];
      Cout[(size_t)gm*ldc + gn] = v;
    }
  }
}

// ---------------- blocked Gauss-Jordan inversion (pivot panel 128) ----------------
// A (n x n, SPD) -> A^{-1} in place. Per round: pivinv -> rowupd(+TC copy) -> mainupd.
__global__ __launch_bounds__(256) void k_pivinv(const double* __restrict__ A, int lda, int n, int k0,
    double* __restrict__ TP){
  extern __shared__ double smem[];
  double* sm = smem;                 // bs rows, ld 129
  double* ck = smem + 128*129;
  double* rk = ck + 128;
  int bs = n - k0; if (bs > 128) bs = 128;
  int tid = threadIdx.x;
  for (int l = tid; l < bs*bs; l += 256){
    int i=l/bs, j=l%bs;
    sm[i*129+j] = A[(size_t)(k0+i)*lda + k0+j];
  }
  __syncthreads();
  for (int k=0;k<bs;k++){
    double d = 1.0/sm[k*129+k];
    if (tid < bs){ ck[tid] = sm[tid*129+k]; rk[tid] = (tid==k) ? d : sm[k*129+tid]*d; }
    __syncthreads();
    for (int l = tid; l < bs*bs; l += 256){
      int i=l/bs, j=l%bs;
      double v;
      if (i==k) v = rk[j];
      else if (j==k) v = -ck[i]*d;
      else v = sm[i*129+j] - ck[i]*rk[j];
      sm[i*129+j] = v;
    }
    __syncthreads();
  }
  for (int l = tid; l < bs*bs; l += 256){
    int i=l/bs, j=l%bs;
    TP[(size_t)i*128+j] = sm[i*129+j];
  }
}

__global__ __launch_bounds__(256) void k_rowupd(double* __restrict__ A, int lda, int n, int k0,
    const double* __restrict__ TP, double* __restrict__ TC){
  int bs = n - k0; if (bs > 128) bs = 128;
  int NBC = (n+63)/64;
  int bx = blockIdx.x, tid = threadIdx.x;
  if (bx >= NBC){
    // copy column slab (rows outside pivot rows) into TC[n][128]
    int r0 = (bx-NBC)*64;
    for (int l = tid; l < 64*bs; l += 256){
      int i = r0 + l/bs, j = l%bs;
      if (i < n && (i < k0 || i >= k0+bs)) TC[(size_t)i*128 + j] = A[(size_t)i*lda + k0+j];
    }
    return;
  }
  int j0 = bx*64;
  __shared__ double TPs[16][129];
  __shared__ double Bs[16][65];
  int tx = tid%16, ty = tid/16;
  double acc[8][4];
  for (int ri=0;ri<8;ri++) for (int c=0;c<4;c++) acc[ri][c]=0.0;
  for (int kp=0; kp<bs; kp+=16){
    for (int l=tid; l<2048; l+=256){
      int kk=l/128, i=l%128;
      TPs[kk][i] = (kp+kk<bs && i<bs) ? TP[(size_t)i*128 + kp+kk] : 0.0;
    }
    for (int l=tid; l<1024; l+=256){
      int kk=l/64, j=l%64;
      Bs[kk][j] = (kp+kk<bs && j0+j<n) ? A[(size_t)(k0+kp+kk)*lda + j0+j] : 0.0;
    }
    __syncthreads();
    #pragma unroll
    for (int kk=0;kk<16;kk++){
      double b0=Bs[kk][tx*4+0],b1=Bs[kk][tx*4+1],b2=Bs[kk][tx*4+2],b3=Bs[kk][tx*4+3];
      #pragma unroll
      for (int ri=0; ri<8; ++ri){
        double a = TPs[kk][ty*8+ri];
        acc[ri][0]+=a*b0; acc[ri][1]+=a*b1; acc[ri][2]+=a*b2; acc[ri][3]+=a*b3;
      }
    }
    __syncthreads();
  }
  for (int ri=0;ri<8;ri++){
    int i = ty*8+ri;
    if (i >= bs) continue;
    for (int c=0;c<4;c++){
      int j = j0 + tx*4 + c;
      if (j >= n) continue;
      double v = (j >= k0 && j < k0+bs) ? TP[(size_t)i*128 + (j-k0)] : acc[ri][c];
      A[(size_t)(k0+i)*lda + j] = v;
    }
  }
}

__global__ __launch_bounds__(256) void k_mainupd(double* __restrict__ A, int lda, int n, int k0,
    const double* __restrict__ TC){
  int bs = n - k0; if (bs > 128) bs = 128;
  int nout = n - bs;
  int tid=threadIdx.x, tx=tid%16, ty=tid/16;
  int m0 = blockIdx.y*64, j0 = blockIdx.x*64;
  __shared__ double As[16][66];
  __shared__ double Bs[16][66];
  double acc[4][4]={};
  for (int kp=0; kp<bs; kp+=16){
    for (int l=tid;l<1024;l+=256){
      int m=l/16,k=l%16; int gm=m0+m, gk=kp+k; double v=0.0;
      if (gm<nout && gk<bs){ int gi=(gm<k0)?gm:gm+bs; v = TC[(size_t)gi*128+gk]; }
      As[k][m]=v;
    }
    for (int l=tid;l<1024;l+=256){
      int k=l/64,j=l%64; int gj=j0+j, gk=kp+k;
      Bs[k][j] = (gj<n && gk<bs)? A[(size_t)(k0+gk)*lda+gj] : 0.0;
    }
    __syncthreads();
    #pragma unroll
    for (int kk=0;kk<16;kk++){
      double a0=As[kk][ty*4+0], a1=As[kk][ty*4+1], a2=As[kk][ty*4+2], a3=As[kk][ty*4+3];
      double b0=Bs[kk][tx*4+0], b1=Bs[kk][tx*4+1], b2=Bs[kk][tx*4+2], b3=Bs[kk][tx*4+3];
      acc[0][0]+=a0*b0; acc[0][1]+=a0*b1; acc[0][2]+=a0*b2; acc[0][3]+=a0*b3;
      acc[1][0]+=a1*b0; acc[1][1]+=a1*b1; acc[1][2]+=a1*b2; acc[1][3]+=a1*b3;
      acc[2][0]+=a2*b0; acc[2][1]+=a2*b1; acc[2][2]+=a2*b2; acc[2][3]+=a2*b3;
      acc[3][0]+=a3*b0; acc[3][1]+=a3*b1; acc[3][2]+=a3*b2; acc[3][3]+=a3*b3;
    }
    __syncthreads();
  }
  for (int i=0;i<4;i++) for (int j=0;j<4;j++){
    int gm=m0+ty*4+i, gj=j0+tx*4+j;
    if (gm<nout && gj<n){
      int gi=(gm<k0)?gm:gm+bs;
      double base = (gj>=k0 && gj<k0+bs)? 0.0 : A[(size_t)gi*lda+gj];
      A[(size_t)gi*lda+gj] = base - acc[i][j];
    }
  }
}

// ---------------- host drivers ----------------
static void gemm_l(hipStream_t s, int transA, int mapA, const double* A, int lda,
                   const double* B, int ldb, const double* Cin, int ldcin,
                   double* Cout, int ldc, int M, int N, int K,
                   const double* al, const double* be){
  dim3 g((N+63)/64, (M+63)/64);
  if (transA){
    if (mapA) k_gemm<1,1><<<g,256,0,s>>>(A,lda,B,ldb,Cin,ldcin,Cout,ldc,M,N,K,al,be);
    else      k_gemm<1,0><<<g,256,0,s>>>(A,lda,B,ldb,Cin,ldcin,Cout,ldc,M,N,K,al,be);
  } else {
    if (mapA) k_gemm<0,1><<<g,256,0,s>>>(A,lda,B,ldb,Cin,ldcin,Cout,ldc,M,N,K,al,be);
    else      k_gemm<0,0><<<g,256,0,s>>>(A,lda,B,ldb,Cin,ldcin,Cout,ldc,M,N,K,al,be);
  }
}

static void gj_inv(hipStream_t s, double* A, int lda, int n, double* TP, double* TC){
  for (int k0 = 0; k0 < n; k0 += 128){
    int bs = n - k0; if (bs > 128) bs = 128;
    k_pivinv<<<1,256,134144,s>>>(A,lda,n,k0,TP);
    int NBC = (n+63)/64;
    k_rowupd<<<NBC*2,256,0,s>>>(A,lda,n,k0,TP,TC);
    int nout = n - bs;
    if (nout > 0){
      dim3 g((n+63)/64, (nout+63)/64);
      k_mainupd<<<g,256,0,s>>>(A,lda,n,k0,TC);
    }
  }
}

extern "C" void kernel_launch(void* const* d_in, const int* in_sizes, int n_in,
                              void* d_out, int out_size, void* d_ws, size_t ws_size,
                              hipStream_t stream){
  const float* Up   = (const float*)d_in[0];
  const float* Yp   = (const float*)d_in[1];
  const float* Uf   = (const float*)d_in[2];
  const float* Yf   = (const float*)d_in[3];
  // d_in[4] = IPI : unused (projector handled analytically)
  const float* q    = (const float*)d_in[5];
  const float* r    = (const float*)d_in[6];
  const float* lam  = (const float*)d_in[7];
  const float* yref = (const float*)d_in[8];
  const float* uref = (const float*)d_in[9];
  const float* u_ini= (const float*)d_in[10];
  const float* y_ini= (const float*)d_in[11];
  float* out = (float*)d_out;

  double* W = (double*)d_ws;
  size_t o = 0;
  double* Gram = W + o; o += (size_t)NQ*NQ;
  double* M11  = W + o; o += (size_t)KB*KB;      // -> M11^{-1}
  double* T12  = W + o; o += (size_t)KB*KP;      // M12
  double* G1   = W + o; o += (size_t)KB*KP;      // M11i @ M12
  double* SP   = W + o; o += (size_t)KP*KP;      // -> S'^{-1}
  double* R1   = W + o; o += (size_t)KU*NRHS;    // [J | Ud] -> [X1;X2] x [Z|Zc]
  double* U1   = W + o; o += (size_t)KB*NRHS;
  double* X2b  = W + o; o += (size_t)KP*NRHS;
  double* Sm   = W + o; o += (size_t)NC*NC;      // -> S^{-1}
  double* dM   = W + o; o += (size_t)KB*NBATCH;
  double* rhs2 = W + o; o += (size_t)NC*NBATCH;
  double* tAc  = W + o; o += (size_t)NC*NBATCH;
  double* P1   = W + o; o += (size_t)KB*NBATCH;
  double* BUZ  = W + o; o += (size_t)KB*NC;
  double* TP   = W + o; o += (size_t)128*128;
  double* TC   = W + o; o += (size_t)KB*128;
  double* cst  = W + o; o += 16;
  if (ws_size < o*sizeof(double)) return;

  const double *C1 = &cst[0], *C0 = &cst[1], *Cm1 = &cst[2];
  const double *Cis = &cst[4], *Cmis = &cst[5], *Cis2 = &cst[6], *Cmis2 = &cst[7];

  k_consts<<<1,1,0,stream>>>(lam, cst);
  k_gram<<<190,256,0,stream>>>(Yf, Uf, Up, Yp, Gram);
  k_asm_M11<<<(KB*KB+255)/256,256,0,stream>>>(Gram, q, r, cst, M11);
  k_asm_M12<<<(KB*KP+255)/256,256,0,stream>>>(Gram, cst, T12);
  k_asm_R1J<<<(KU*NC+255)/256,256,0,stream>>>(Gram, R1);
  k_build_d<<<(KB*NBATCH+255)/256,256,0,stream>>>(q, r, yref, uref, dM);
  k_build_negb<<<(NC*NBATCH+255)/256,256,0,stream>>>(u_ini, y_ini, rhs2);

  // Ud = [B;P] @ d  -> R1 cols 400..527 (A read from Gram via row map)
  gemm_l(stream, 0, 1, Gram, NQ, dM, NBATCH, R1+NC, NRHS, R1+NC, NRHS, KU, NBATCH, KB, C1, C0);

  // M11 -> M11^{-1}
  gj_inv(stream, M11, KB, KB, TP, TC);

  // G1 = M11i @ M12 ; S' = M12^T @ G1 ; S' -> S'^{-1}
  gemm_l(stream, 0, 0, M11, KB, T12, KP, G1, KP, G1, KP, KB, KP, KB, C1, C0);
  gemm_l(stream, 1, 0, T12, KP, G1, KP, SP, KP, SP, KP, KP, KP, KB, C1, C0);
  gj_inv(stream, SP, KP, KP, TP, TC);

  // Apply M^{-1} to R1 (528 cols):
  gemm_l(stream, 0, 0, M11, KB, R1, NRHS, U1, NRHS, U1, NRHS, KB, NRHS, KB, C1, C0);        // U1 = M11i z1
  gemm_l(stream, 1, 0, T12, KP, U1, NRHS, R1+(size_t)KB*NRHS, NRHS,
         R1+(size_t)KB*NRHS, NRHS, KP, NRHS, KB, C1, Cm1);                                   // V = M12^T U1 - z2
  gemm_l(stream, 0, 0, SP, KP, R1+(size_t)KB*NRHS, NRHS, X2b, NRHS, X2b, NRHS,
         KP, NRHS, KP, C1, C0);                                                              // X2 = S'i V
  k_dcopy<<<((KP*NRHS)+255)/256,256,0,stream>>>(X2b, R1+(size_t)KB*NRHS, KP*NRHS);
  gemm_l(stream, 0, 0, G1, KP, X2b, NRHS, U1, NRHS, R1, NRHS, KB, NRHS, KP, Cm1, C1);        // X1 = U1 - G1 X2

  // S = (1/s) AA^T - (1/s^2) J^T Z ; -> S^{-1}
  gemm_l(stream, 1, 1, Gram+800, NQ, R1, NRHS, Gram+(size_t)800*NQ+800, NQ,
         Sm, NC, NC, NC, KU, Cmis2, Cis);
  gj_inv(stream, Sm, NC, NC, TP, TC);

  // rhs2 = (1/s) A B^T d - b - (1/s^2) J^T Zc ; nu = S^{-1} rhs2 (-> tAc)
  gemm_l(stream, 0, 0, Gram+(size_t)800*NQ, NQ, dM, NBATCH, rhs2, NBATCH,
         tAc, NBATCH, NC, NBATCH, KB, Cis, C1);
  gemm_l(stream, 1, 1, Gram+800, NQ, R1+NC, NRHS, tAc, NBATCH,
         rhs2, NBATCH, NC, NBATCH, KU, Cmis2, C1);
  gemm_l(stream, 0, 0, Sm, NC, rhs2, NBATCH, tAc, NBATCH, tAc, NBATCH,
         NC, NBATCH, NC, C1, C0);                                                            // nu

  // Bg = (1/s)(BB^T d - BA^T nu) - (1/s^2)(BU Zc - BU Z nu)
  gemm_l(stream, 0, 0, Gram, NQ, dM, NBATCH, P1, NBATCH, P1, NBATCH,
         KB, NBATCH, KB, Cis, C0);
  gemm_l(stream, 0, 0, Gram+800, NQ, tAc, NBATCH, P1, NBATCH, P1, NBATCH,
         KB, NBATCH, NC, Cmis, C1);
  gemm_l(stream, 1, 1, Gram, NQ, R1+NC, NRHS, P1, NBATCH, P1, NBATCH,
         KB, NBATCH, KU, Cmis2, C1);
  gemm_l(stream, 1, 1, Gram, NQ, R1, NRHS, BUZ, NC, BUZ, NC,
         KB, NC, KU, C1, C0);
  gemm_l(stream, 0, 0, BUZ, NC, tAc, NBATCH, P1, NBATCH, P1, NBATCH,
         KB, NBATCH, NC, Cis2, C1);

  k_out<<<(102400+255)/256,256,0,stream>>>(P1, out);
}

// Round 3
// 23293.448 us; speedup vs baseline: 1.2423x; 1.2423x over previous
//
#include <hip/hip_runtime.h>
#include <math.h>

#define NDIMX 2941
#define NQ 1200
#define KB 800
#define KP 720
#define KU 1520
#define NC 400
#define NBT 128
#define NRHS 528
#define GRID 256
#define TPB 256

__device__ __forceinline__ int umap(int x){ return (x < 1200) ? x : x - 720; }

__device__ __forceinline__ const float* qrowp(int rr, const float* Yf, const float* Uf,
                                              const float* Up, const float* Yp){
  if (rr < 480) return Yf + (size_t)rr*NDIMX;
  if (rr < 800) return Uf + (size_t)(rr-480)*NDIMX;
  if (rr < 960) return Up + (size_t)(rr-800)*NDIMX;
  return Yp + (size_t)(rr-960)*NDIMX;
}

// ---------------- device-scope grid barrier (one counter slot per instance) ----------------
__device__ __forceinline__ void gbar(unsigned* cnt, int& id){
  __syncthreads();
  if (threadIdx.x == 0){
    __threadfence();
    unsigned* c = cnt + id;
    __hip_atomic_fetch_add(c, 1u, __ATOMIC_ACQ_REL, __HIP_MEMORY_SCOPE_AGENT);
    while (__hip_atomic_load(c, __ATOMIC_ACQUIRE, __HIP_MEMORY_SCOPE_AGENT) < (unsigned)GRID){
      __builtin_amdgcn_s_sleep(4);
    }
    __threadfence();
  }
  __syncthreads();
  id++;
}

// ---------------- Gram stage (f32 acc, f64 store), 64x64 tiles over 256 blocks ----------------
__device__ void st_gram(const float* Yf, const float* Uf, const float* Up, const float* Yp,
                        double* G, double* shd){
  float* At = (float*)shd;          // [32][65]
  float* Bt = At + 32*65;           // [32][65]
  const int NT = (NQ + 63)/64;      // 19
  const int ntri = NT*(NT+1)/2;     // 190
  int tid = threadIdx.x, tx = tid%16, ty = tid/16;
  for (int t = blockIdx.x; t < ntri; t += gridDim.x){
    int rem = t, ti = 0;
    while (rem >= ti+1){ rem -= ti+1; ++ti; }
    int tj = rem;
    int i0 = ti*64, j0 = tj*64;
    float acc[4][4] = {};
    for (int k0 = 0; k0 < NDIMX; k0 += 32){
      for (int l = tid; l < 2048; l += TPB){
        int r2 = l >> 5, k = l & 31;
        int gr = i0 + r2, gk = k0 + k;
        At[k*65 + r2] = (gr < NQ && gk < NDIMX) ? qrowp(gr,Yf,Uf,Up,Yp)[gk] : 0.f;
      }
      if (ti != tj){
        for (int l = tid; l < 2048; l += TPB){
          int r2 = l >> 5, k = l & 31;
          int gr = j0 + r2, gk = k0 + k;
          Bt[k*65 + r2] = (gr < NQ && gk < NDIMX) ? qrowp(gr,Yf,Uf,Up,Yp)[gk] : 0.f;
        }
      }
      __syncthreads();
      float* Bp = (ti==tj) ? At : Bt;
      #pragma unroll 8
      for (int kk=0; kk<32; ++kk){
        float a0=At[kk*65+ty*4+0],a1=At[kk*65+ty*4+1],a2=At[kk*65+ty*4+2],a3=At[kk*65+ty*4+3];
        float b0=Bp[kk*65+tx*4+0],b1=Bp[kk*65+tx*4+1],b2=Bp[kk*65+tx*4+2],b3=Bp[kk*65+tx*4+3];
        acc[0][0]+=a0*b0; acc[0][1]+=a0*b1; acc[0][2]+=a0*b2; acc[0][3]+=a0*b3;
        acc[1][0]+=a1*b0; acc[1][1]+=a1*b1; acc[1][2]+=a1*b2; acc[1][3]+=a1*b3;
        acc[2][0]+=a2*b0; acc[2][1]+=a2*b1; acc[2][2]+=a2*b2; acc[2][3]+=a2*b3;
        acc[3][0]+=a3*b0; acc[3][1]+=a3*b1; acc[3][2]+=a3*b2; acc[3][3]+=a3*b3;
      }
      __syncthreads();
    }
    for (int i=0;i<4;i++) for (int j=0;j<4;j++){
      int gi = i0 + ty*4 + i, gj = j0 + tx*4 + j;
      if (gi < NQ && gj < NQ){
        double v = (double)acc[i][j];
        G[(size_t)gi*NQ+gj] = v;
        G[(size_t)gj*NQ+gi] = v;
      }
    }
  }
}

// ---------------- fused elementwise assembly ----------------
__device__ void st_assemble(const double* G, const float* q, const float* r, double isg,
    const float* yref, const float* uref, const float* u_ini, const float* y_ini,
    double* M11, double* T12, double* R1, double* dM, double* rhs2){
  int tid0 = blockIdx.x*TPB + threadIdx.x, stride = gridDim.x*TPB;
  for (int idx=tid0; idx<KB*KB; idx+=stride){
    int i=idx/KB, j=idx-i*KB;
    double v = G[(size_t)i*NQ+j]*isg;
    if (i==j){ double w=(i<480)?(double)q[i%12]:(double)r[(i-480)%8]; v += 0.5/w; }
    M11[idx]=v;
  }
  for (int idx=tid0; idx<KB*KP; idx+=stride){
    int i=idx/KP, j=idx-i*KP;
    int pc=(j<400)?(800+j):(80+j);
    T12[idx]=G[(size_t)i*NQ+pc]*isg;
  }
  for (int idx=tid0; idx<KU*NC; idx+=stride){
    int i=idx/NC, j=idx-i*NC;
    R1[(size_t)i*NRHS+j]=G[(size_t)umap(i)*NQ+800+j];
  }
  for (int idx=tid0; idx<KB*NBT; idx+=stride){
    int k=idx/NBT, t=idx-k*NBT;
    dM[idx]=(k<480)? 2.0*(double)q[k%12]*(double)yref[(size_t)t*480+k]
                   : 2.0*(double)r[(k-480)%8]*(double)uref[(size_t)t*320+(k-480)];
  }
  for (int idx=tid0; idx<NC*NBT; idx+=stride){
    int j=idx/NBT, t=idx-j*NBT;
    rhs2[idx]= -((j<160)?(double)u_ini[(size_t)t*160+j]:(double)y_ini[(size_t)t*240+(j-160)]);
  }
}

// ---------------- generic f64 GEMM stage, 64x64 tiles distributed over blocks ----------------
template<int TRANSA, int MAPA>
__device__ void dgemm(const double* __restrict__ A, int lda, const double* __restrict__ B, int ldb,
    const double* __restrict__ Cin, int ldcin, double* __restrict__ Cout, int ldc,
    int M, int N, int K, double alpha, double beta, double* shd){
  double* As = shd;          // [16][66]
  double* Bs = shd + 1056;   // [16][66]
  int tid = threadIdx.x, tx = tid%16, ty = tid/16;
  int ntn = (N+63)>>6, ntm = (M+63)>>6;
  for (int t = blockIdx.x; t < ntm*ntn; t += gridDim.x){
    int m0 = (t/ntn)*64, n0 = (t%ntn)*64;
    double acc[4][4] = {};
    for (int k0 = 0; k0 < K; k0 += 16){
      if (TRANSA == 0){
        for (int l = tid; l < 1024; l += TPB){
          int m = l/16, k = l%16;
          int gm = m0+m, gk = k0+k;
          double v = 0.0;
          if (gm<M && gk<K){ int row = MAPA ? umap(gm) : gm; v = A[(size_t)row*lda + gk]; }
          As[k*66+m] = v;
        }
      } else {
        for (int l = tid; l < 1024; l += TPB){
          int k = l/64, m = l%64;
          int gm = m0+m, gk = k0+k;
          double v = 0.0;
          if (gm<M && gk<K){ int row = MAPA ? umap(gk) : gk; v = A[(size_t)row*lda + gm]; }
          As[k*66+m] = v;
        }
      }
      for (int l = tid; l < 1024; l += TPB){
        int k = l/64, n = l%64;
        int gn = n0+n, gk = k0+k;
        Bs[k*66+n] = (gn<N && gk<K) ? B[(size_t)gk*ldb + gn] : 0.0;
      }
      __syncthreads();
      #pragma unroll
      for (int kk=0; kk<16; ++kk){
        double a0=As[kk*66+ty*4+0], a1=As[kk*66+ty*4+1], a2=As[kk*66+ty*4+2], a3=As[kk*66+ty*4+3];
        double b0=Bs[kk*66+tx*4+0], b1=Bs[kk*66+tx*4+1], b2=Bs[kk*66+tx*4+2], b3=Bs[kk*66+tx*4+3];
        acc[0][0]+=a0*b0; acc[0][1]+=a0*b1; acc[0][2]+=a0*b2; acc[0][3]+=a0*b3;
        acc[1][0]+=a1*b0; acc[1][1]+=a1*b1; acc[1][2]+=a1*b2; acc[1][3]+=a1*b3;
        acc[2][0]+=a2*b0; acc[2][1]+=a2*b1; acc[2][2]+=a2*b2; acc[2][3]+=a2*b3;
        acc[3][0]+=a3*b0; acc[3][1]+=a3*b1; acc[3][2]+=a3*b2; acc[3][3]+=a3*b3;
      }
      __syncthreads();
    }
    for (int i=0;i<4;i++) for (int j=0;j<4;j++){
      int gm = m0 + ty*4 + i, gn = n0 + tx*4 + j;
      if (gm < M && gn < N){
        double v = alpha*acc[i][j];
        if (beta != 0.0) v += beta*Cin[(size_t)gm*ldcin + gn];
        Cout[(size_t)gm*ldc + gn] = v;
      }
    }
  }
}

// ---------------- blocked Gauss-Jordan (panel 64) pieces ----------------
__device__ void gj_pivinv(const double* A, int lda, int n, int k0, double* TP, double* shd){
  int bs = n - k0; if (bs > 64) bs = 64;
  double* sm = shd;            // [64][65]
  double* ck = shd + 64*65;    // [64]
  double* rk = ck + 64;        // [64]
  int tid = threadIdx.x;
  for (int l = tid; l < bs*bs; l += TPB){
    int i=l/bs, j=l-i*bs;
    sm[i*65+j] = A[(size_t)(k0+i)*lda + k0+j];
  }
  __syncthreads();
  for (int k=0;k<bs;k++){
    double d = 1.0/sm[k*65+k];
    if (tid < bs){ ck[tid] = sm[tid*65+k]; rk[tid] = (tid==k) ? d : sm[k*65+tid]*d; }
    __syncthreads();
    for (int l = tid; l < bs*bs; l += TPB){
      int i=l/bs, j=l-i*bs;
      double v;
      if (i==k) v = rk[j];
      else if (j==k) v = -ck[i]*d;
      else v = sm[i*65+j] - ck[i]*rk[j];
      sm[i*65+j] = v;
    }
    __syncthreads();
  }
  for (int l = tid; l < bs*bs; l += TPB){
    int i=l/bs, j=l-i*bs;
    TP[i*64+j] = sm[i*65+j];
  }
}

__device__ void gj_colcopy(const double* A, int lda, int n, int k0, int bs, double* TC){
  // compact copy of the panel-column slab for rows OUTSIDE the panel (done by blocks 1..)
  if (blockIdx.x == 0) return;
  int tot = (n - bs)*bs;
  for (int l = (blockIdx.x-1)*TPB + threadIdx.x; l < tot; l += (gridDim.x-1)*TPB){
    int rr = l/bs, j = l - rr*bs;
    int i = (rr < k0) ? rr : rr + bs;
    TC[(size_t)rr*64 + j] = A[(size_t)i*lda + k0 + j];
  }
}

__device__ void gj_rowupd(double* A, int lda, int n, int k0, int bs, const double* TP, double* shd){
  double* TPs = shd;          // [16][66] (k, row)
  double* Bs  = shd + 1056;   // [16][66] (k, col)
  int tid = threadIdx.x, tx = tid%16, ty = tid/16;
  int ntc = (n+63)>>6;
  for (int t = blockIdx.x; t < ntc; t += gridDim.x){
    int j0 = t*64;
    double acc[4][4] = {};
    for (int kp=0; kp<bs; kp+=16){
      for (int l=tid; l<1024; l+=TPB){
        int k=l/64, m=l-(l/64)*64;
        TPs[k*66+m] = (m<bs && kp+k<bs) ? TP[m*64 + kp+k] : 0.0;
      }
      for (int l=tid; l<1024; l+=TPB){
        int k=l/64, j=l-(l/64)*64;
        Bs[k*66+j] = (kp+k<bs && j0+j<n) ? A[(size_t)(k0+kp+k)*lda + j0+j] : 0.0;
      }
      __syncthreads();
      #pragma unroll
      for (int kk=0; kk<16; ++kk){
        double a0=TPs[kk*66+ty*4+0], a1=TPs[kk*66+ty*4+1], a2=TPs[kk*66+ty*4+2], a3=TPs[kk*66+ty*4+3];
        double b0=Bs[kk*66+tx*4+0],  b1=Bs[kk*66+tx*4+1],  b2=Bs[kk*66+tx*4+2],  b3=Bs[kk*66+tx*4+3];
        acc[0][0]+=a0*b0; acc[0][1]+=a0*b1; acc[0][2]+=a0*b2; acc[0][3]+=a0*b3;
        acc[1][0]+=a1*b0; acc[1][1]+=a1*b1; acc[1][2]+=a1*b2; acc[1][3]+=a1*b3;
        acc[2][0]+=a2*b0; acc[2][1]+=a2*b1; acc[2][2]+=a2*b2; acc[2][3]+=a2*b3;
        acc[3][0]+=a3*b0; acc[3][1]+=a3*b1; acc[3][2]+=a3*b2; acc[3][3]+=a3*b3;
      }
      __syncthreads();
    }
    for (int i=0;i<4;i++) for (int j=0;j<4;j++){
      int gi = ty*4+i, gj = j0 + tx*4 + j;
      if (gi < bs && gj < n){
        double v = (gj >= k0 && gj < k0+bs) ? TP[gi*64 + (gj-k0)] : acc[i][j];
        A[(size_t)(k0+gi)*lda + gj] = v;
      }
    }
  }
}

__device__ void gj_mainupd(double* A, int lda, int n, int k0, int bs, const double* TC, double* shd){
  double* As = shd;          // [16][66]
  double* Bs = shd + 1056;   // [16][66]
  int tid = threadIdx.x, tx = tid%16, ty = tid/16;
  int nout = n - bs;
  int ntn = (n+63)>>6, ntm = (nout+63)>>6;
  for (int t = blockIdx.x; t < ntm*ntn; t += gridDim.x){
    int m0 = (t/ntn)*64, j0 = (t%ntn)*64;
    double acc[4][4] = {};
    for (int kp=0; kp<bs; kp+=16){
      for (int l=tid; l<1024; l+=TPB){
        int m=l/16, k=l-(l/16)*16;
        As[k*66+m] = (m0+m<nout && kp+k<bs) ? TC[(size_t)(m0+m)*64 + kp+k] : 0.0;
      }
      for (int l=tid; l<1024; l+=TPB){
        int k=l/64, j=l-(l/64)*64;
        Bs[k*66+j] = (kp+k<bs && j0+j<n) ? A[(size_t)(k0+kp+k)*lda + j0+j] : 0.0;
      }
      __syncthreads();
      #pragma unroll
      for (int kk=0; kk<16; ++kk){
        double a0=As[kk*66+ty*4+0], a1=As[kk*66+ty*4+1], a2=As[kk*66+ty*4+2], a3=As[kk*66+ty*4+3];
        double b0=Bs[kk*66+tx*4+0], b1=Bs[kk*66+tx*4+1], b2=Bs[kk*66+tx*4+2], b3=Bs[kk*66+tx*4+3];
        acc[0][0]+=a0*b0; acc[0][1]+=a0*b1; acc[0][2]+=a0*b2; acc[0][3]+=a0*b3;
        acc[1][0]+=a1*b0; acc[1][1]+=a1*b1; acc[1][2]+=a1*b2; acc[1][3]+=a1*b3;
        acc[2][0]+=a2*b0; acc[2][1]+=a2*b1; acc[2][2]+=a2*b2; acc[2][3]+=a2*b3;
        acc[3][0]+=a3*b0; acc[3][1]+=a3*b1; acc[3][2]+=a3*b2; acc[3][3]+=a3*b3;
      }
      __syncthreads();
    }
    for (int i=0;i<4;i++) for (int j=0;j<4;j++){
      int gm = m0+ty*4+i, gj = j0+tx*4+j;
      if (gm < nout && gj < n){
        int gi = (gm < k0) ? gm : gm + bs;
        double base = (gj >= k0 && gj < k0+bs) ? 0.0 : A[(size_t)gi*lda + gj];
        A[(size_t)gi*lda + gj] = base - acc[i][j];
      }
    }
  }
}

__device__ void gj_inv(double* A, int n, double* TP, double* TC, double* shd,
                       unsigned* cnt, int& bid){
  for (int k0 = 0; k0 < n; k0 += 64){
    int bs = n - k0; if (bs > 64) bs = 64;
    if (blockIdx.x == 0) gj_pivinv(A, n, n, k0, TP, shd);
    else gj_colcopy(A, n, n, k0, bs, TC);
    gbar(cnt, bid);
    gj_rowupd(A, n, n, k0, bs, TP, shd);
    gbar(cnt, bid);
    if (n - bs > 0){
      gj_mainupd(A, n, n, k0, bs, TC, shd);
      gbar(cnt, bid);
    }
  }
}

// ---------------- misc stages ----------------
__device__ void st_copy(const double* s, double* d, size_t n){
  for (size_t i = (size_t)blockIdx.x*TPB + threadIdx.x; i < n; i += (size_t)gridDim.x*TPB)
    d[i] = s[i];
}

__device__ void st_out(const double* Bg, float* out){
  int stride = gridDim.x*TPB;
  for (int idx = blockIdx.x*TPB + threadIdx.x; idx < 128*800; idx += stride){
    if (idx < 128*320){
      int t = idx/320, i = idx-(idx/320)*320;
      out[idx] = (float)Bg[(size_t)(480+i)*NBT + t];
    } else {
      int l = idx - 128*320;
      int t = l/480, i = l-(l/480)*480;
      out[idx] = (float)Bg[(size_t)i*NBT + t];
    }
  }
}

// ---------------- init kernel ----------------
__global__ __launch_bounds__(256) void k_init(unsigned* cnt){
  int i = blockIdx.x*256 + threadIdx.x;
  if (i < 1024) cnt[i] = 0;
}

// ---------------- mega kernel ----------------
__global__ __launch_bounds__(256) void k_mega(
    const float* Up, const float* Yp, const float* Uf, const float* Yf,
    const float* q, const float* r, const float* lam,
    const float* yref, const float* uref, const float* u_ini, const float* y_ini,
    float* out,
    double* Gram, double* M11, double* T12, double* G1, double* SP, double* R1,
    double* U1, double* X2b, double* Sm, double* dM, double* rhs2, double* tAc,
    double* P1, double* BUZ, double* TP, double* TC, unsigned* cnt){
  __shared__ double shd[4288];
  int bid = 0;
  double sg = 2.0*(double)lam[0];
  double isg = 1.0/sg, isg2 = isg*isg;

  // 1. Gram
  st_gram(Yf, Uf, Up, Yp, Gram, shd);
  gbar(cnt, bid);
  // 2. assembly
  st_assemble(Gram, q, r, isg, yref, uref, u_ini, y_ini, M11, T12, R1, dM, rhs2);
  gbar(cnt, bid);
  // 3. Ud = [B;P] @ dM -> R1 cols 400..527
  dgemm<0,1>(Gram, NQ, dM, NBT, R1+NC, NRHS, R1+NC, NRHS, KU, NBT, KB, 1.0, 0.0, shd);
  gbar(cnt, bid);
  // 4. M11 -> M11^{-1}
  gj_inv(M11, KB, TP, TC, shd, cnt, bid);
  // 5. G1 = M11i @ T12
  dgemm<0,0>(M11, KB, T12, KP, G1, KP, G1, KP, KB, KP, KB, 1.0, 0.0, shd);
  gbar(cnt, bid);
  // 6. SP = T12^T @ G1
  dgemm<1,0>(T12, KP, G1, KP, SP, KP, SP, KP, KP, KP, KB, 1.0, 0.0, shd);
  gbar(cnt, bid);
  // 7. SP -> SP^{-1}
  gj_inv(SP, KP, TP, TC, shd, cnt, bid);
  // 8. U1 = M11i @ R1top
  dgemm<0,0>(M11, KB, R1, NRHS, U1, NRHS, U1, NRHS, KB, NRHS, KB, 1.0, 0.0, shd);
  gbar(cnt, bid);
  // 9. V = T12^T @ U1 - R1low  (into R1low)
  dgemm<1,0>(T12, KP, U1, NRHS, R1+(size_t)KB*NRHS, NRHS, R1+(size_t)KB*NRHS, NRHS,
             KP, NRHS, KB, 1.0, -1.0, shd);
  gbar(cnt, bid);
  // 10. X2 = SPi @ V
  dgemm<0,0>(SP, KP, R1+(size_t)KB*NRHS, NRHS, X2b, NRHS, X2b, NRHS, KP, NRHS, KP, 1.0, 0.0, shd);
  gbar(cnt, bid);
  // 11. X1 = U1 - G1 @ X2 (into R1top); copy X2 -> R1low (independent regions)
  st_copy(X2b, R1+(size_t)KB*NRHS, (size_t)KP*NRHS);
  dgemm<0,0>(G1, KP, X2b, NRHS, U1, NRHS, R1, NRHS, KB, NRHS, KP, -1.0, 1.0, shd);
  gbar(cnt, bid);
  // 12. Sm = isg*AA^T - isg2*(J^T Z)
  dgemm<1,1>(Gram+800, NQ, R1, NRHS, Gram+(size_t)800*NQ+800, NQ, Sm, NC,
             NC, NC, KU, -isg2, isg, shd);
  gbar(cnt, bid);
  // 13. Sm -> Sm^{-1}
  gj_inv(Sm, NC, TP, TC, shd, cnt, bid);
  // 14. tAc = isg*(A B^T d) - b
  dgemm<0,0>(Gram+(size_t)800*NQ, NQ, dM, NBT, rhs2, NBT, tAc, NBT, NC, NBT, KB, isg, 1.0, shd);
  gbar(cnt, bid);
  // 15. rhs2 = tAc - isg2*(J^T Zc)
  dgemm<1,1>(Gram+800, NQ, R1+NC, NRHS, tAc, NBT, rhs2, NBT, NC, NBT, KU, -isg2, 1.0, shd);
  gbar(cnt, bid);
  // 16. nu = Smi @ rhs2 -> tAc
  dgemm<0,0>(Sm, NC, rhs2, NBT, tAc, NBT, tAc, NBT, NC, NBT, NC, 1.0, 0.0, shd);
  gbar(cnt, bid);
  // 17. P1 = isg*(BB^T d)
  dgemm<0,0>(Gram, NQ, dM, NBT, P1, NBT, P1, NBT, KB, NBT, KB, isg, 0.0, shd);
  gbar(cnt, bid);
  // 18. P1 -= isg*(BA^T nu)
  dgemm<0,0>(Gram+800, NQ, tAc, NBT, P1, NBT, P1, NBT, KB, NBT, NC, -isg, 1.0, shd);
  gbar(cnt, bid);
  // 19. P1 -= isg2*(BU Zc)
  dgemm<1,1>(Gram, NQ, R1+NC, NRHS, P1, NBT, P1, NBT, KB, NBT, KU, -isg2, 1.0, shd);
  gbar(cnt, bid);
  // 20. BUZ = BU @ Z
  dgemm<1,1>(Gram, NQ, R1, NRHS, BUZ, NC, BUZ, NC, KB, NC, KU, 1.0, 0.0, shd);
  gbar(cnt, bid);
  // 21. P1 += isg2*(BUZ nu)
  dgemm<0,0>(BUZ, NC, tAc, NBT, P1, NBT, P1, NBT, KB, NBT, NC, isg2, 1.0, shd);
  gbar(cnt, bid);
  // 22. output
  st_out(P1, out);
}

extern "C" void kernel_launch(void* const* d_in, const int* in_sizes, int n_in,
                              void* d_out, int out_size, void* d_ws, size_t ws_size,
                              hipStream_t stream){
  const float* Up   = (const float*)d_in[0];
  const float* Yp   = (const float*)d_in[1];
  const float* Uf   = (const float*)d_in[2];
  const float* Yf   = (const float*)d_in[3];
  // d_in[4] = IPI : unused (projector handled analytically)
  const float* q    = (const float*)d_in[5];
  const float* r    = (const float*)d_in[6];
  const float* lam  = (const float*)d_in[7];
  const float* yref = (const float*)d_in[8];
  const float* uref = (const float*)d_in[9];
  const float* u_ini= (const float*)d_in[10];
  const float* y_ini= (const float*)d_in[11];
  float* out = (float*)d_out;

  double* W = (double*)d_ws;
  size_t o = 0;
  double* Gram = W + o; o += (size_t)NQ*NQ;
  double* M11  = W + o; o += (size_t)KB*KB;
  double* T12  = W + o; o += (size_t)KB*KP;
  double* G1   = W + o; o += (size_t)KB*KP;
  double* SP   = W + o; o += (size_t)KP*KP;
  double* R1   = W + o; o += (size_t)KU*NRHS;
  double* U1   = W + o; o += (size_t)KB*NRHS;
  double* X2b  = W + o; o += (size_t)KP*NRHS;
  double* Sm   = W + o; o += (size_t)NC*NC;
  double* dM   = W + o; o += (size_t)KB*NBT;
  double* rhs2 = W + o; o += (size_t)NC*NBT;
  double* tAc  = W + o; o += (size_t)NC*NBT;
  double* P1   = W + o; o += (size_t)KB*NBT;
  double* BUZ  = W + o; o += (size_t)KB*NC;
  double* TP   = W + o; o += (size_t)64*64;
  double* TC   = W + o; o += (size_t)KB*64;
  unsigned* cnt = (unsigned*)(W + o); o += 512;
  if (ws_size < o*sizeof(double)) return;

  k_init<<<4,256,0,stream>>>(cnt);
  k_mega<<<GRID,TPB,0,stream>>>(Up,Yp,Uf,Yf,q,r,lam,yref,uref,u_ini,y_ini,out,
      Gram,M11,T12,G1,SP,R1,U1,X2b,Sm,dM,rhs2,tAc,P1,BUZ,TP,TC,cnt);
}

// Round 4
// 12315.330 us; speedup vs baseline: 2.3496x; 1.8914x over previous
//
#include <hip/hip_runtime.h>
#include <math.h>

#define NDIMX 2941
#define NQ 1200
#define KB 800
#define KP 720
#define KU 1520
#define NC 400
#define NBT 128
#define NRHS 528
#define GRID 256
#define TPB 256

__device__ __forceinline__ int umap(int x){ return (x < 1200) ? x : x - 720; }

__device__ __forceinline__ const float* qrowp(int rr, const float* Yf, const float* Uf,
                                              const float* Up, const float* Yp){
  if (rr < 480) return Yf + (size_t)rr*NDIMX;
  if (rr < 800) return Uf + (size_t)(rr-480)*NDIMX;
  if (rr < 960) return Up + (size_t)(rr-800)*NDIMX;
  return Yp + (size_t)(rr-960)*NDIMX;
}

// ---------------- device-scope grid barrier ----------------
// Arrive: single RELEASE add (one wbL2 per block). Poll: RELAXED loads
// (no cache invalidation per iteration!). Exit: ONE acquire load to
// invalidate stale L1/L2 lines before consuming other blocks' writes.
__device__ __forceinline__ void gbar(unsigned* cnt, int& id){
  __syncthreads();
  if (threadIdx.x == 0){
    unsigned* c = cnt + id;
    __hip_atomic_fetch_add(c, 1u, __ATOMIC_RELEASE, __HIP_MEMORY_SCOPE_AGENT);
    while (__hip_atomic_load(c, __ATOMIC_RELAXED, __HIP_MEMORY_SCOPE_AGENT) < (unsigned)GRID){
      __builtin_amdgcn_s_sleep(16);
    }
    (void)__hip_atomic_load(c, __ATOMIC_ACQUIRE, __HIP_MEMORY_SCOPE_AGENT);
  }
  __syncthreads();
  id++;
}

// ---------------- Gram stage (f32 acc, f64 store), 64x64 tiles over 256 blocks ----------------
__device__ void st_gram(const float* Yf, const float* Uf, const float* Up, const float* Yp,
                        double* G, double* shd){
  float* At = (float*)shd;          // [32][65]
  float* Bt = At + 32*65;           // [32][65]
  const int NT = (NQ + 63)/64;      // 19
  const int ntri = NT*(NT+1)/2;     // 190
  int tid = threadIdx.x, tx = tid%16, ty = tid/16;
  for (int t = blockIdx.x; t < ntri; t += gridDim.x){
    int rem = t, ti = 0;
    while (rem >= ti+1){ rem -= ti+1; ++ti; }
    int tj = rem;
    int i0 = ti*64, j0 = tj*64;
    float acc[4][4] = {};
    for (int k0 = 0; k0 < NDIMX; k0 += 32){
      for (int l = tid; l < 2048; l += TPB){
        int r2 = l >> 5, k = l & 31;
        int gr = i0 + r2, gk = k0 + k;
        At[k*65 + r2] = (gr < NQ && gk < NDIMX) ? qrowp(gr,Yf,Uf,Up,Yp)[gk] : 0.f;
      }
      if (ti != tj){
        for (int l = tid; l < 2048; l += TPB){
          int r2 = l >> 5, k = l & 31;
          int gr = j0 + r2, gk = k0 + k;
          Bt[k*65 + r2] = (gr < NQ && gk < NDIMX) ? qrowp(gr,Yf,Uf,Up,Yp)[gk] : 0.f;
        }
      }
      __syncthreads();
      float* Bp = (ti==tj) ? At : Bt;
      #pragma unroll 8
      for (int kk=0; kk<32; ++kk){
        float a0=At[kk*65+ty*4+0],a1=At[kk*65+ty*4+1],a2=At[kk*65+ty*4+2],a3=At[kk*65+ty*4+3];
        float b0=Bp[kk*65+tx*4+0],b1=Bp[kk*65+tx*4+1],b2=Bp[kk*65+tx*4+2],b3=Bp[kk*65+tx*4+3];
        acc[0][0]+=a0*b0; acc[0][1]+=a0*b1; acc[0][2]+=a0*b2; acc[0][3]+=a0*b3;
        acc[1][0]+=a1*b0; acc[1][1]+=a1*b1; acc[1][2]+=a1*b2; acc[1][3]+=a1*b3;
        acc[2][0]+=a2*b0; acc[2][1]+=a2*b1; acc[2][2]+=a2*b2; acc[2][3]+=a2*b3;
        acc[3][0]+=a3*b0; acc[3][1]+=a3*b1; acc[3][2]+=a3*b2; acc[3][3]+=a3*b3;
      }
      __syncthreads();
    }
    for (int i=0;i<4;i++) for (int j=0;j<4;j++){
      int gi = i0 + ty*4 + i, gj = j0 + tx*4 + j;
      if (gi < NQ && gj < NQ){
        double v = (double)acc[i][j];
        G[(size_t)gi*NQ+gj] = v;
        G[(size_t)gj*NQ+gi] = v;
      }
    }
  }
}

// ---------------- fused elementwise assembly ----------------
__device__ void st_assemble(const double* G, const float* q, const float* r, double isg,
    const float* yref, const float* uref, const float* u_ini, const float* y_ini,
    double* M11, double* T12, double* R1, double* dM, double* rhs2){
  int tid0 = blockIdx.x*TPB + threadIdx.x, stride = gridDim.x*TPB;
  for (int idx=tid0; idx<KB*KB; idx+=stride){
    int i=idx/KB, j=idx-i*KB;
    double v = G[(size_t)i*NQ+j]*isg;
    if (i==j){ double w=(i<480)?(double)q[i%12]:(double)r[(i-480)%8]; v += 0.5/w; }
    M11[idx]=v;
  }
  for (int idx=tid0; idx<KB*KP; idx+=stride){
    int i=idx/KP, j=idx-i*KP;
    int pc=(j<400)?(800+j):(80+j);
    T12[idx]=G[(size_t)i*NQ+pc]*isg;
  }
  for (int idx=tid0; idx<KU*NC; idx+=stride){
    int i=idx/NC, j=idx-i*NC;
    R1[(size_t)i*NRHS+j]=G[(size_t)umap(i)*NQ+800+j];
  }
  for (int idx=tid0; idx<KB*NBT; idx+=stride){
    int k=idx/NBT, t=idx-k*NBT;
    dM[idx]=(k<480)? 2.0*(double)q[k%12]*(double)yref[(size_t)t*480+k]
                   : 2.0*(double)r[(k-480)%8]*(double)uref[(size_t)t*320+(k-480)];
  }
  for (int idx=tid0; idx<NC*NBT; idx+=stride){
    int j=idx/NBT, t=idx-j*NBT;
    rhs2[idx]= -((j<160)?(double)u_ini[(size_t)t*160+j]:(double)y_ini[(size_t)t*240+(j-160)]);
  }
}

// ---------------- generic f64 GEMM stage, 64x64 tiles distributed over blocks ----------------
template<int TRANSA, int MAPA>
__device__ void dgemm(const double* __restrict__ A, int lda, const double* __restrict__ B, int ldb,
    const double* __restrict__ Cin, int ldcin, double* __restrict__ Cout, int ldc,
    int M, int N, int K, double alpha, double beta, double* shd){
  double* As = shd;          // [16][66]
  double* Bs = shd + 1056;   // [16][66]
  int tid = threadIdx.x, tx = tid%16, ty = tid/16;
  int ntn = (N+63)>>6, ntm = (M+63)>>6;
  for (int t = blockIdx.x; t < ntm*ntn; t += gridDim.x){
    int m0 = (t/ntn)*64, n0 = (t%ntn)*64;
    double acc[4][4] = {};
    for (int k0 = 0; k0 < K; k0 += 16){
      if (TRANSA == 0){
        for (int l = tid; l < 1024; l += TPB){
          int m = l/16, k = l%16;
          int gm = m0+m, gk = k0+k;
          double v = 0.0;
          if (gm<M && gk<K){ int row = MAPA ? umap(gm) : gm; v = A[(size_t)row*lda + gk]; }
          As[k*66+m] = v;
        }
      } else {
        for (int l = tid; l < 1024; l += TPB){
          int k = l/64, m = l%64;
          int gm = m0+m, gk = k0+k;
          double v = 0.0;
          if (gm<M && gk<K){ int row = MAPA ? umap(gk) : gk; v = A[(size_t)row*lda + gm]; }
          As[k*66+m] = v;
        }
      }
      for (int l = tid; l < 1024; l += TPB){
        int k = l/64, n = l%64;
        int gn = n0+n, gk = k0+k;
        Bs[k*66+n] = (gn<N && gk<K) ? B[(size_t)gk*ldb + gn] : 0.0;
      }
      __syncthreads();
      #pragma unroll
      for (int kk=0; kk<16; ++kk){
        double a0=As[kk*66+ty*4+0], a1=As[kk*66+ty*4+1], a2=As[kk*66+ty*4+2], a3=As[kk*66+ty*4+3];
        double b0=Bs[kk*66+tx*4+0], b1=Bs[kk*66+tx*4+1], b2=Bs[kk*66+tx*4+2], b3=Bs[kk*66+tx*4+3];
        acc[0][0]+=a0*b0; acc[0][1]+=a0*b1; acc[0][2]+=a0*b2; acc[0][3]+=a0*b3;
        acc[1][0]+=a1*b0; acc[1][1]+=a1*b1; acc[1][2]+=a1*b2; acc[1][3]+=a1*b3;
        acc[2][0]+=a2*b0; acc[2][1]+=a2*b1; acc[2][2]+=a2*b2; acc[2][3]+=a2*b3;
        acc[3][0]+=a3*b0; acc[3][1]+=a3*b1; acc[3][2]+=a3*b2; acc[3][3]+=a3*b3;
      }
      __syncthreads();
    }
    for (int i=0;i<4;i++) for (int j=0;j<4;j++){
      int gm = m0 + ty*4 + i, gn = n0 + tx*4 + j;
      if (gm < M && gn < N){
        double v = alpha*acc[i][j];
        if (beta != 0.0) v += beta*Cin[(size_t)gm*ldcin + gn];
        Cout[(size_t)gm*ldc + gn] = v;
      }
    }
  }
}

// ---------------- blocked Gauss-Jordan (panel 64) pieces ----------------
__device__ void gj_pivinv(const double* A, int lda, int n, int k0, double* TP, double* shd){
  int bs = n - k0; if (bs > 64) bs = 64;
  double* sm = shd;            // [64][65]
  double* ck = shd + 64*65;    // [64]
  double* rk = ck + 64;        // [64]
  int tid = threadIdx.x;
  for (int l = tid; l < bs*bs; l += TPB){
    int i=l/bs, j=l-i*bs;
    sm[i*65+j] = A[(size_t)(k0+i)*lda + k0+j];
  }
  __syncthreads();
  for (int k=0;k<bs;k++){
    double d = 1.0/sm[k*65+k];
    if (tid < bs){ ck[tid] = sm[tid*65+k]; rk[tid] = (tid==k) ? d : sm[k*65+tid]*d; }
    __syncthreads();
    for (int l = tid; l < bs*bs; l += TPB){
      int i=l/bs, j=l-i*bs;
      double v;
      if (i==k) v = rk[j];
      else if (j==k) v = -ck[i]*d;
      else v = sm[i*65+j] - ck[i]*rk[j];
      sm[i*65+j] = v;
    }
    __syncthreads();
  }
  for (int l = tid; l < bs*bs; l += TPB){
    int i=l/bs, j=l-i*bs;
    TP[i*64+j] = sm[i*65+j];
  }
}

__device__ void gj_colcopy(const double* A, int lda, int n, int k0, int bs, double* TC){
  if (blockIdx.x == 0) return;
  int tot = (n - bs)*bs;
  for (int l = (blockIdx.x-1)*TPB + threadIdx.x; l < tot; l += (gridDim.x-1)*TPB){
    int rr = l/bs, j = l - rr*bs;
    int i = (rr < k0) ? rr : rr + bs;
    TC[(size_t)rr*64 + j] = A[(size_t)i*lda + k0 + j];
  }
}

__device__ void gj_rowupd(double* A, int lda, int n, int k0, int bs, const double* TP, double* shd){
  double* TPs = shd;          // [16][66] (k, row)
  double* Bs  = shd + 1056;   // [16][66] (k, col)
  int tid = threadIdx.x, tx = tid%16, ty = tid/16;
  int ntc = (n+63)>>6;
  for (int t = blockIdx.x; t < ntc; t += gridDim.x){
    int j0 = t*64;
    double acc[4][4] = {};
    for (int kp=0; kp<bs; kp+=16){
      for (int l=tid; l<1024; l+=TPB){
        int k=l/64, m=l-(l/64)*64;
        TPs[k*66+m] = (m<bs && kp+k<bs) ? TP[m*64 + kp+k] : 0.0;
      }
      for (int l=tid; l<1024; l+=TPB){
        int k=l/64, j=l-(l/64)*64;
        Bs[k*66+j] = (kp+k<bs && j0+j<n) ? A[(size_t)(k0+kp+k)*lda + j0+j] : 0.0;
      }
      __syncthreads();
      #pragma unroll
      for (int kk=0; kk<16; ++kk){
        double a0=TPs[kk*66+ty*4+0], a1=TPs[kk*66+ty*4+1], a2=TPs[kk*66+ty*4+2], a3=TPs[kk*66+ty*4+3];
        double b0=Bs[kk*66+tx*4+0],  b1=Bs[kk*66+tx*4+1],  b2=Bs[kk*66+tx*4+2],  b3=Bs[kk*66+tx*4+3];
        acc[0][0]+=a0*b0; acc[0][1]+=a0*b1; acc[0][2]+=a0*b2; acc[0][3]+=a0*b3;
        acc[1][0]+=a1*b0; acc[1][1]+=a1*b1; acc[1][2]+=a1*b2; acc[1][3]+=a1*b3;
        acc[2][0]+=a2*b0; acc[2][1]+=a2*b1; acc[2][2]+=a2*b2; acc[2][3]+=a2*b3;
        acc[3][0]+=a3*b0; acc[3][1]+=a3*b1; acc[3][2]+=a3*b2; acc[3][3]+=a3*b3;
      }
      __syncthreads();
    }
    for (int i=0;i<4;i++) for (int j=0;j<4;j++){
      int gi = ty*4+i, gj = j0 + tx*4 + j;
      if (gi < bs && gj < n){
        double v = (gj >= k0 && gj < k0+bs) ? TP[gi*64 + (gj-k0)] : acc[i][j];
        A[(size_t)(k0+gi)*lda + gj] = v;
      }
    }
  }
}

__device__ void gj_mainupd(double* A, int lda, int n, int k0, int bs, const double* TC, double* shd){
  double* As = shd;          // [16][66]
  double* Bs = shd + 1056;   // [16][66]
  int tid = threadIdx.x, tx = tid%16, ty = tid/16;
  int nout = n - bs;
  int ntn = (n+63)>>6, ntm = (nout+63)>>6;
  for (int t = blockIdx.x; t < ntm*ntn; t += gridDim.x){
    int m0 = (t/ntn)*64, j0 = (t%ntn)*64;
    double acc[4][4] = {};
    for (int kp=0; kp<bs; kp+=16){
      for (int l=tid; l<1024; l+=TPB){
        int m=l/16, k=l-(l/16)*16;
        As[k*66+m] = (m0+m<nout && kp+k<bs) ? TC[(size_t)(m0+m)*64 + kp+k] : 0.0;
      }
      for (int l=tid; l<1024; l+=TPB){
        int k=l/64, j=l-(l/64)*64;
        Bs[k*66+j] = (kp+k<bs && j0+j<n) ? A[(size_t)(k0+kp+k)*lda + j0+j] : 0.0;
      }
      __syncthreads();
      #pragma unroll
      for (int kk=0; kk<16; ++kk){
        double a0=As[kk*66+ty*4+0], a1=As[kk*66+ty*4+1], a2=As[kk*66+ty*4+2], a3=As[kk*66+ty*4+3];
        double b0=Bs[kk*66+tx*4+0], b1=Bs[kk*66+tx*4+1], b2=Bs[kk*66+tx*4+2], b3=Bs[kk*66+tx*4+3];
        acc[0][0]+=a0*b0; acc[0][1]+=a0*b1; acc[0][2]+=a0*b2; acc[0][3]+=a0*b3;
        acc[1][0]+=a1*b0; acc[1][1]+=a1*b1; acc[1][2]+=a1*b2; acc[1][3]+=a1*b3;
        acc[2][0]+=a2*b0; acc[2][1]+=a2*b1; acc[2][2]+=a2*b2; acc[2][3]+=a2*b3;
        acc[3][0]+=a3*b0; acc[3][1]+=a3*b1; acc[3][2]+=a3*b2; acc[3][3]+=a3*b3;
      }
      __syncthreads();
    }
    for (int i=0;i<4;i++) for (int j=0;j<4;j++){
      int gm = m0+ty*4+i, gj = j0+tx*4+j;
      if (gm < nout && gj < n){
        int gi = (gm < k0) ? gm : gm + bs;
        double base = (gj >= k0 && gj < k0+bs) ? 0.0 : A[(size_t)gi*lda + gj];
        A[(size_t)gi*lda + gj] = base - acc[i][j];
      }
    }
  }
}

__device__ void gj_inv(double* A, int n, double* TP, double* TC, double* shd,
                       unsigned* cnt, int& bid){
  for (int k0 = 0; k0 < n; k0 += 64){
    int bs = n - k0; if (bs > 64) bs = 64;
    if (blockIdx.x == 0) gj_pivinv(A, n, n, k0, TP, shd);
    else gj_colcopy(A, n, n, k0, bs, TC);
    gbar(cnt, bid);
    gj_rowupd(A, n, n, k0, bs, TP, shd);
    gbar(cnt, bid);
    if (n - bs > 0){
      gj_mainupd(A, n, n, k0, bs, TC, shd);
      gbar(cnt, bid);
    }
  }
}

// ---------------- misc stages ----------------
__device__ void st_copy(const double* s, double* d, size_t n){
  for (size_t i = (size_t)blockIdx.x*TPB + threadIdx.x; i < n; i += (size_t)gridDim.x*TPB)
    d[i] = s[i];
}

__device__ void st_out(const double* Bg, float* out){
  int stride = gridDim.x*TPB;
  for (int idx = blockIdx.x*TPB + threadIdx.x; idx < 128*800; idx += stride){
    if (idx < 128*320){
      int t = idx/320, i = idx-(idx/320)*320;
      out[idx] = (float)Bg[(size_t)(480+i)*NBT + t];
    } else {
      int l = idx - 128*320;
      int t = l/480, i = l-(l/480)*480;
      out[idx] = (float)Bg[(size_t)i*NBT + t];
    }
  }
}

// ---------------- init kernel ----------------
__global__ __launch_bounds__(256) void k_init(unsigned* cnt){
  int i = blockIdx.x*256 + threadIdx.x;
  if (i < 1024) cnt[i] = 0;
}

// ---------------- mega kernel ----------------
__global__ __launch_bounds__(256) void k_mega(
    const float* Up, const float* Yp, const float* Uf, const float* Yf,
    const float* q, const float* r, const float* lam,
    const float* yref, const float* uref, const float* u_ini, const float* y_ini,
    float* out,
    double* Gram, double* M11, double* T12, double* G1, double* SP, double* R1,
    double* U1, double* X2b, double* Sm, double* dM, double* rhs2, double* tAc,
    double* P1, double* BUZ, double* TP, double* TC, unsigned* cnt){
  __shared__ double shd[4288];
  int bid = 0;
  double sg = 2.0*(double)lam[0];
  double isg = 1.0/sg, isg2 = isg*isg;

  // 1. Gram
  st_gram(Yf, Uf, Up, Yp, Gram, shd);
  gbar(cnt, bid);
  // 2. assembly
  st_assemble(Gram, q, r, isg, yref, uref, u_ini, y_ini, M11, T12, R1, dM, rhs2);
  gbar(cnt, bid);
  // 3. Ud = [B;P] @ dM -> R1 cols 400..527
  dgemm<0,1>(Gram, NQ, dM, NBT, R1+NC, NRHS, R1+NC, NRHS, KU, NBT, KB, 1.0, 0.0, shd);
  gbar(cnt, bid);
  // 4. M11 -> M11^{-1}
  gj_inv(M11, KB, TP, TC, shd, cnt, bid);
  // 5. G1 = M11i @ T12
  dgemm<0,0>(M11, KB, T12, KP, G1, KP, G1, KP, KB, KP, KB, 1.0, 0.0, shd);
  gbar(cnt, bid);
  // 6. SP = T12^T @ G1
  dgemm<1,0>(T12, KP, G1, KP, SP, KP, SP, KP, KP, KP, KB, 1.0, 0.0, shd);
  gbar(cnt, bid);
  // 7. SP -> SP^{-1}
  gj_inv(SP, KP, TP, TC, shd, cnt, bid);
  // 8. U1 = M11i @ R1top
  dgemm<0,0>(M11, KB, R1, NRHS, U1, NRHS, U1, NRHS, KB, NRHS, KB, 1.0, 0.0, shd);
  gbar(cnt, bid);
  // 9. V = T12^T @ U1 - R1low  (into R1low)
  dgemm<1,0>(T12, KP, U1, NRHS, R1+(size_t)KB*NRHS, NRHS, R1+(size_t)KB*NRHS, NRHS,
             KP, NRHS, KB, 1.0, -1.0, shd);
  gbar(cnt, bid);
  // 10. X2 = SPi @ V
  dgemm<0,0>(SP, KP, R1+(size_t)KB*NRHS, NRHS, X2b, NRHS, X2b, NRHS, KP, NRHS, KP, 1.0, 0.0, shd);
  gbar(cnt, bid);
  // 11. X1 = U1 - G1 @ X2 (into R1top); copy X2 -> R1low (independent regions)
  st_copy(X2b, R1+(size_t)KB*NRHS, (size_t)KP*NRHS);
  dgemm<0,0>(G1, KP, X2b, NRHS, U1, NRHS, R1, NRHS, KB, NRHS, KP, -1.0, 1.0, shd);
  gbar(cnt, bid);
  // 12. Sm = isg*AA^T - isg2*(J^T Z)
  dgemm<1,1>(Gram+800, NQ, R1, NRHS, Gram+(size_t)800*NQ+800, NQ, Sm, NC,
             NC, NC, KU, -isg2, isg, shd);
  gbar(cnt, bid);
  // 13. Sm -> Sm^{-1}
  gj_inv(Sm, NC, TP, TC, shd, cnt, bid);
  // 14. tAc = isg*(A B^T d) - b
  dgemm<0,0>(Gram+(size_t)800*NQ, NQ, dM, NBT, rhs2, NBT, tAc, NBT, NC, NBT, KB, isg, 1.0, shd);
  gbar(cnt, bid);
  // 15. rhs2 = tAc - isg2*(J^T Zc)
  dgemm<1,1>(Gram+800, NQ, R1+NC, NRHS, tAc, NBT, rhs2, NBT, NC, NBT, KU, -isg2, 1.0, shd);
  gbar(cnt, bid);
  // 16. nu = Smi @ rhs2 -> tAc
  dgemm<0,0>(Sm, NC, rhs2, NBT, tAc, NBT, tAc, NBT, NC, NBT, NC, 1.0, 0.0, shd);
  gbar(cnt, bid);
  // 17. P1 = isg*(BB^T d)
  dgemm<0,0>(Gram, NQ, dM, NBT, P1, NBT, P1, NBT, KB, NBT, KB, isg, 0.0, shd);
  gbar(cnt, bid);
  // 18. P1 -= isg*(BA^T nu)
  dgemm<0,0>(Gram+800, NQ, tAc, NBT, P1, NBT, P1, NBT, KB, NBT, NC, -isg, 1.0, shd);
  gbar(cnt, bid);
  // 19. P1 -= isg2*(BU Zc)
  dgemm<1,1>(Gram, NQ, R1+NC, NRHS, P1, NBT, P1, NBT, KB, NBT, KU, -isg2, 1.0, shd);
  gbar(cnt, bid);
  // 20. BUZ = BU @ Z
  dgemm<1,1>(Gram, NQ, R1, NRHS, BUZ, NC, BUZ, NC, KB, NC, KU, 1.0, 0.0, shd);
  gbar(cnt, bid);
  // 21. P1 += isg2*(BUZ nu)
  dgemm<0,0>(BUZ, NC, tAc, NBT, P1, NBT, P1, NBT, KB, NBT, NC, isg2, 1.0, shd);
  gbar(cnt, bid);
  // 22. output
  st_out(P1, out);
}

extern "C" void kernel_launch(void* const* d_in, const int* in_sizes, int n_in,
                              void* d_out, int out_size, void* d_ws, size_t ws_size,
                              hipStream_t stream){
  const float* Up   = (const float*)d_in[0];
  const float* Yp   = (const float*)d_in[1];
  const float* Uf   = (const float*)d_in[2];
  const float* Yf   = (const float*)d_in[3];
  // d_in[4] = IPI : unused (projector handled analytically)
  const float* q    = (const float*)d_in[5];
  const float* r    = (const float*)d_in[6];
  const float* lam  = (const float*)d_in[7];
  const float* yref = (const float*)d_in[8];
  const float* uref = (const float*)d_in[9];
  const float* u_ini= (const float*)d_in[10];
  const float* y_ini= (const float*)d_in[11];
  float* out = (float*)d_out;

  double* W = (double*)d_ws;
  size_t o = 0;
  double* Gram = W + o; o += (size_t)NQ*NQ;
  double* M11  = W + o; o += (size_t)KB*KB;
  double* T12  = W + o; o += (size_t)KB*KP;
  double* G1   = W + o; o += (size_t)KB*KP;
  double* SP   = W + o; o += (size_t)KP*KP;
  double* R1   = W + o; o += (size_t)KU*NRHS;
  double* U1   = W + o; o += (size_t)KB*NRHS;
  double* X2b  = W + o; o += (size_t)KP*NRHS;
  double* Sm   = W + o; o += (size_t)NC*NC;
  double* dM   = W + o; o += (size_t)KB*NBT;
  double* rhs2 = W + o; o += (size_t)NC*NBT;
  double* tAc  = W + o; o += (size_t)NC*NBT;
  double* P1   = W + o; o += (size_t)KB*NBT;
  double* BUZ  = W + o; o += (size_t)KB*NC;
  double* TP   = W + o; o += (size_t)64*64;
  double* TC   = W + o; o += (size_t)KB*64;
  unsigned* cnt = (unsigned*)(W + o); o += 512;
  if (ws_size < o*sizeof(double)) return;

  k_init<<<4,256,0,stream>>>(cnt);
  k_mega<<<GRID,TPB,0,stream>>>(Up,Yp,Uf,Yf,q,r,lam,yref,uref,u_ini,y_ini,out,
      Gram,M11,T12,G1,SP,R1,U1,X2b,Sm,dM,rhs2,tAc,P1,BUZ,TP,TC,cnt);
}

// Round 5
// 10802.409 us; speedup vs baseline: 2.6787x; 1.1401x over previous
//
#include <hip/hip_runtime.h>
#include <math.h>

#define NDIMX 2941
#define NQ 1200
#define KB 800
#define KP 720
#define KU 1520
#define NC 400
#define NBT 128
#define NRHS 528
#define GRID 256
#define TPB 256

__device__ __forceinline__ int umap(int x){ return (x < 1200) ? x : x - 720; }

__device__ __forceinline__ const float* qrowp(int rr, const float* Yf, const float* Uf,
                                              const float* Up, const float* Yp){
  if (rr < 480) return Yf + (size_t)rr*NDIMX;
  if (rr < 800) return Uf + (size_t)(rr-480)*NDIMX;
  if (rr < 960) return Up + (size_t)(rr-800)*NDIMX;
  return Yp + (size_t)(rr-960)*NDIMX;
}

// ---------------- device-scope grid barrier ----------------
// Arrive: SYSTEM-scope release add (RMW lives at the device coherence point).
// Poll: SYSTEM-scope RELAXED load — bypasses L1 AND L2, reads the coherent
// copy directly; no per-iteration cache invalidation, and no stale-L2 hang.
// Exit: one AGENT acquire to invalidate L1/L2 before consuming peers' data.
__device__ __forceinline__ void gbar(unsigned* cnt, int& id){
  __syncthreads();
  if (threadIdx.x == 0){
    unsigned* c = cnt + id;
    __hip_atomic_fetch_add(c, 1u, __ATOMIC_RELEASE, __HIP_MEMORY_SCOPE_SYSTEM);
    while (__hip_atomic_load(c, __ATOMIC_RELAXED, __HIP_MEMORY_SCOPE_SYSTEM) < (unsigned)GRID){
      __builtin_amdgcn_s_sleep(8);
    }
    (void)__hip_atomic_load(c, __ATOMIC_ACQUIRE, __HIP_MEMORY_SCOPE_AGENT);
  }
  __syncthreads();
  id++;
}

// ---------------- Gram stage (f32 acc, f64 store), 64x64 tiles over 256 blocks ----------------
__device__ void st_gram(const float* Yf, const float* Uf, const float* Up, const float* Yp,
                        double* G, double* shd){
  float* At = (float*)shd;          // [32][65]
  float* Bt = At + 32*65;           // [32][65]
  const int NT = (NQ + 63)/64;      // 19
  const int ntri = NT*(NT+1)/2;     // 190
  int tid = threadIdx.x, tx = tid%16, ty = tid/16;
  for (int t = blockIdx.x; t < ntri; t += gridDim.x){
    int rem = t, ti = 0;
    while (rem >= ti+1){ rem -= ti+1; ++ti; }
    int tj = rem;
    int i0 = ti*64, j0 = tj*64;
    float acc[4][4] = {};
    for (int k0 = 0; k0 < NDIMX; k0 += 32){
      for (int l = tid; l < 2048; l += TPB){
        int r2 = l >> 5, k = l & 31;
        int gr = i0 + r2, gk = k0 + k;
        At[k*65 + r2] = (gr < NQ && gk < NDIMX) ? qrowp(gr,Yf,Uf,Up,Yp)[gk] : 0.f;
      }
      if (ti != tj){
        for (int l = tid; l < 2048; l += TPB){
          int r2 = l >> 5, k = l & 31;
          int gr = j0 + r2, gk = k0 + k;
          Bt[k*65 + r2] = (gr < NQ && gk < NDIMX) ? qrowp(gr,Yf,Uf,Up,Yp)[gk] : 0.f;
        }
      }
      __syncthreads();
      float* Bp = (ti==tj) ? At : Bt;
      #pragma unroll 8
      for (int kk=0; kk<32; ++kk){
        float a0=At[kk*65+ty*4+0],a1=At[kk*65+ty*4+1],a2=At[kk*65+ty*4+2],a3=At[kk*65+ty*4+3];
        float b0=Bp[kk*65+tx*4+0],b1=Bp[kk*65+tx*4+1],b2=Bp[kk*65+tx*4+2],b3=Bp[kk*65+tx*4+3];
        acc[0][0]+=a0*b0; acc[0][1]+=a0*b1; acc[0][2]+=a0*b2; acc[0][3]+=a0*b3;
        acc[1][0]+=a1*b0; acc[1][1]+=a1*b1; acc[1][2]+=a1*b2; acc[1][3]+=a1*b3;
        acc[2][0]+=a2*b0; acc[2][1]+=a2*b1; acc[2][2]+=a2*b2; acc[2][3]+=a2*b3;
        acc[3][0]+=a3*b0; acc[3][1]+=a3*b1; acc[3][2]+=a3*b2; acc[3][3]+=a3*b3;
      }
      __syncthreads();
    }
    for (int i=0;i<4;i++) for (int j=0;j<4;j++){
      int gi = i0 + ty*4 + i, gj = j0 + tx*4 + j;
      if (gi < NQ && gj < NQ){
        double v = (double)acc[i][j];
        G[(size_t)gi*NQ+gj] = v;
        G[(size_t)gj*NQ+gi] = v;
      }
    }
  }
}

// ---------------- fused elementwise assembly ----------------
__device__ void st_assemble(const double* G, const float* q, const float* r, double isg,
    const float* yref, const float* uref, const float* u_ini, const float* y_ini,
    double* M11, double* T12, double* R1, double* dM, double* rhs2){
  int tid0 = blockIdx.x*TPB + threadIdx.x, stride = gridDim.x*TPB;
  for (int idx=tid0; idx<KB*KB; idx+=stride){
    int i=idx/KB, j=idx-i*KB;
    double v = G[(size_t)i*NQ+j]*isg;
    if (i==j){ double w=(i<480)?(double)q[i%12]:(double)r[(i-480)%8]; v += 0.5/w; }
    M11[idx]=v;
  }
  for (int idx=tid0; idx<KB*KP; idx+=stride){
    int i=idx/KP, j=idx-i*KP;
    int pc=(j<400)?(800+j):(80+j);
    T12[idx]=G[(size_t)i*NQ+pc]*isg;
  }
  for (int idx=tid0; idx<KU*NC; idx+=stride){
    int i=idx/NC, j=idx-i*NC;
    R1[(size_t)i*NRHS+j]=G[(size_t)umap(i)*NQ+800+j];
  }
  for (int idx=tid0; idx<KB*NBT; idx+=stride){
    int k=idx/NBT, t=idx-k*NBT;
    dM[idx]=(k<480)? 2.0*(double)q[k%12]*(double)yref[(size_t)t*480+k]
                   : 2.0*(double)r[(k-480)%8]*(double)uref[(size_t)t*320+(k-480)];
  }
  for (int idx=tid0; idx<NC*NBT; idx+=stride){
    int j=idx/NBT, t=idx-j*NBT;
    rhs2[idx]= -((j<160)?(double)u_ini[(size_t)t*160+j]:(double)y_ini[(size_t)t*240+(j-160)]);
  }
}

// ---------------- generic f64 GEMM, 64x64 tiles, double-buffered k-slices ----------------
template<int TRANSA, int MAPA>
__device__ void dgemm(const double* __restrict__ A, int lda, const double* __restrict__ B, int ldb,
    const double* __restrict__ Cin, int ldcin, double* __restrict__ Cout, int ldc,
    int M, int N, int K, double alpha, double beta, double* shd){
  double* As = shd;          // [16][66]
  double* Bs = shd + 1056;   // [16][66]
  int tid = threadIdx.x, tx = tid%16, ty = tid/16;
  int ntn = (N+63)>>6, ntm = (M+63)>>6;
  for (int t = blockIdx.x; t < ntm*ntn; t += gridDim.x){
    int m0 = (t/ntn)*64, n0 = (t%ntn)*64;
    double acc[4][4] = {};
    double ra[4], rb[4];
    auto loadAB = [&](int k0v){
      #pragma unroll
      for (int s=0;s<4;s++){
        int l = tid + s*TPB;
        if (TRANSA==0){
          int m = l>>4, k = l&15;
          int gm = m0+m, gk = k0v+k;
          double v = 0.0;
          if (gm<M && gk<K){ int row = MAPA ? umap(gm) : gm; v = A[(size_t)row*lda + gk]; }
          ra[s] = v;
        } else {
          int k = l>>6, m = l&63;
          int gm = m0+m, gk = k0v+k;
          double v = 0.0;
          if (gm<M && gk<K){ int row = MAPA ? umap(gk) : gk; v = A[(size_t)row*lda + gm]; }
          ra[s] = v;
        }
        int kb = l>>6, n = l&63;
        int gn = n0+n, gkb = k0v+kb;
        rb[s] = (gn<N && gkb<K) ? B[(size_t)gkb*ldb + gn] : 0.0;
      }
    };
    loadAB(0);
    for (int k0 = 0; k0 < K; k0 += 16){
      __syncthreads();
      #pragma unroll
      for (int s=0;s<4;s++){
        int l = tid + s*TPB;
        if (TRANSA==0){ int m=l>>4, k=l&15; As[k*66+m] = ra[s]; }
        else          { int k=l>>6, m=l&63; As[k*66+m] = ra[s]; }
        int kb=l>>6, n=l&63; Bs[kb*66+n] = rb[s];
      }
      __syncthreads();
      if (k0+16 < K) loadAB(k0+16);
      #pragma unroll
      for (int kk=0; kk<16; ++kk){
        double a0=As[kk*66+ty*4+0], a1=As[kk*66+ty*4+1], a2=As[kk*66+ty*4+2], a3=As[kk*66+ty*4+3];
        double b0=Bs[kk*66+tx*4+0], b1=Bs[kk*66+tx*4+1], b2=Bs[kk*66+tx*4+2], b3=Bs[kk*66+tx*4+3];
        acc[0][0]+=a0*b0; acc[0][1]+=a0*b1; acc[0][2]+=a0*b2; acc[0][3]+=a0*b3;
        acc[1][0]+=a1*b0; acc[1][1]+=a1*b1; acc[1][2]+=a1*b2; acc[1][3]+=a1*b3;
        acc[2][0]+=a2*b0; acc[2][1]+=a2*b1; acc[2][2]+=a2*b2; acc[2][3]+=a2*b3;
        acc[3][0]+=a3*b0; acc[3][1]+=a3*b1; acc[3][2]+=a3*b2; acc[3][3]+=a3*b3;
      }
      __syncthreads();
    }
    for (int i=0;i<4;i++) for (int j=0;j<4;j++){
      int gm = m0 + ty*4 + i, gn = n0 + tx*4 + j;
      if (gm < M && gn < N){
        double v = alpha*acc[i][j];
        if (beta != 0.0) v += beta*Cin[(size_t)gm*ldcin + gn];
        Cout[(size_t)gm*ldc + gn] = v;
      }
    }
  }
}

// ---------------- blocked Gauss-Jordan (panel 64) pieces ----------------
__device__ void gj_pivinv(const double* A, int lda, int n, int k0, double* TP, double* shd){
  int bs = n - k0; if (bs > 64) bs = 64;
  double* sm = shd;            // [64][65]
  double* ck = shd + 64*65;    // [64]
  double* rk = ck + 64;        // [64]
  int tid = threadIdx.x;
  for (int l = tid; l < bs*bs; l += TPB){
    int i=l/bs, j=l-i*bs;
    sm[i*65+j] = A[(size_t)(k0+i)*lda + k0+j];
  }
  __syncthreads();
  for (int k=0;k<bs;k++){
    double d = 1.0/sm[k*65+k];
    if (tid < bs){ ck[tid] = sm[tid*65+k]; rk[tid] = (tid==k) ? d : sm[k*65+tid]*d; }
    __syncthreads();
    for (int l = tid; l < bs*bs; l += TPB){
      int i=l/bs, j=l-i*bs;
      double v;
      if (i==k) v = rk[j];
      else if (j==k) v = -ck[i]*d;
      else v = sm[i*65+j] - ck[i]*rk[j];
      sm[i*65+j] = v;
    }
    __syncthreads();
  }
  for (int l = tid; l < bs*bs; l += TPB){
    int i=l/bs, j=l-i*bs;
    TP[i*64+j] = sm[i*65+j];
  }
}

__device__ void gj_colcopy(const double* A, int lda, int n, int k0, int bs, double* TC){
  if (blockIdx.x == 0) return;
  int tot = (n - bs)*bs;
  for (int l = (blockIdx.x-1)*TPB + threadIdx.x; l < tot; l += (gridDim.x-1)*TPB){
    int rr = l/bs, j = l - rr*bs;
    int i = (rr < k0) ? rr : rr + bs;
    TC[(size_t)rr*64 + j] = A[(size_t)i*lda + k0 + j];
  }
}

__device__ void gj_rowupd(double* A, int lda, int n, int k0, int bs, const double* TP, double* shd){
  double* TPs = shd;          // [16][66] (k, row)
  double* Bs  = shd + 1056;   // [16][66] (k, col)
  int tid = threadIdx.x, tx = tid%16, ty = tid/16;
  int ntc = (n+63)>>6;
  for (int t = blockIdx.x; t < ntc; t += gridDim.x){
    int j0 = t*64;
    double acc[4][4] = {};
    for (int kp=0; kp<bs; kp+=16){
      for (int l=tid; l<1024; l+=TPB){
        int k=l/64, m=l-(l/64)*64;
        TPs[k*66+m] = (m<bs && kp+k<bs) ? TP[m*64 + kp+k] : 0.0;
      }
      for (int l=tid; l<1024; l+=TPB){
        int k=l/64, j=l-(l/64)*64;
        Bs[k*66+j] = (kp+k<bs && j0+j<n) ? A[(size_t)(k0+kp+k)*lda + j0+j] : 0.0;
      }
      __syncthreads();
      #pragma unroll
      for (int kk=0; kk<16; ++kk){
        double a0=TPs[kk*66+ty*4+0], a1=TPs[kk*66+ty*4+1], a2=TPs[kk*66+ty*4+2], a3=TPs[kk*66+ty*4+3];
        double b0=Bs[kk*66+tx*4+0],  b1=Bs[kk*66+tx*4+1],  b2=Bs[kk*66+tx*4+2],  b3=Bs[kk*66+tx*4+3];
        acc[0][0]+=a0*b0; acc[0][1]+=a0*b1; acc[0][2]+=a0*b2; acc[0][3]+=a0*b3;
        acc[1][0]+=a1*b0; acc[1][1]+=a1*b1; acc[1][2]+=a1*b2; acc[1][3]+=a1*b3;
        acc[2][0]+=a2*b0; acc[2][1]+=a2*b1; acc[2][2]+=a2*b2; acc[2][3]+=a2*b3;
        acc[3][0]+=a3*b0; acc[3][1]+=a3*b1; acc[3][2]+=a3*b2; acc[3][3]+=a3*b3;
      }
      __syncthreads();
    }
    for (int i=0;i<4;i++) for (int j=0;j<4;j++){
      int gi = ty*4+i, gj = j0 + tx*4 + j;
      if (gi < bs && gj < n){
        double v = (gj >= k0 && gj < k0+bs) ? TP[gi*64 + (gj-k0)] : acc[i][j];
        A[(size_t)(k0+gi)*lda + gj] = v;
      }
    }
  }
}

__device__ void gj_mainupd(double* A, int lda, int n, int k0, int bs, const double* TC, double* shd){
  double* As = shd;          // [16][66]
  double* Bs = shd + 1056;   // [16][66]
  int tid = threadIdx.x, tx = tid%16, ty = tid/16;
  int nout = n - bs;
  int ntn = (n+63)>>6, ntm = (nout+63)>>6;
  for (int t = blockIdx.x; t < ntm*ntn; t += gridDim.x){
    int m0 = (t/ntn)*64, j0 = (t%ntn)*64;
    double acc[4][4] = {};
    for (int kp=0; kp<bs; kp+=16){
      for (int l=tid; l<1024; l+=TPB){
        int m=l/16, k=l-(l/16)*16;
        As[k*66+m] = (m0+m<nout && kp+k<bs) ? TC[(size_t)(m0+m)*64 + kp+k] : 0.0;
      }
      for (int l=tid; l<1024; l+=TPB){
        int k=l/64, j=l-(l/64)*64;
        Bs[k*66+j] = (kp+k<bs && j0+j<n) ? A[(size_t)(k0+kp+k)*lda + j0+j] : 0.0;
      }
      __syncthreads();
      #pragma unroll
      for (int kk=0; kk<16; ++kk){
        double a0=As[kk*66+ty*4+0], a1=As[kk*66+ty*4+1], a2=As[kk*66+ty*4+2], a3=As[kk*66+ty*4+3];
        double b0=Bs[kk*66+tx*4+0], b1=Bs[kk*66+tx*4+1], b2=Bs[kk*66+tx*4+2], b3=Bs[kk*66+tx*4+3];
        acc[0][0]+=a0*b0; acc[0][1]+=a0*b1; acc[0][2]+=a0*b2; acc[0][3]+=a0*b3;
        acc[1][0]+=a1*b0; acc[1][1]+=a1*b1; acc[1][2]+=a1*b2; acc[1][3]+=a1*b3;
        acc[2][0]+=a2*b0; acc[2][1]+=a2*b1; acc[2][2]+=a2*b2; acc[2][3]+=a2*b3;
        acc[3][0]+=a3*b0; acc[3][1]+=a3*b1; acc[3][2]+=a3*b2; acc[3][3]+=a3*b3;
      }
      __syncthreads();
    }
    for (int i=0;i<4;i++) for (int j=0;j<4;j++){
      int gm = m0+ty*4+i, gj = j0+tx*4+j;
      if (gm < nout && gj < n){
        int gi = (gm < k0) ? gm : gm + bs;
        double base = (gj >= k0 && gj < k0+bs) ? 0.0 : A[(size_t)gi*lda + gj];
        A[(size_t)gi*lda + gj] = base - acc[i][j];
      }
    }
  }
}

__device__ void gj_inv(double* A, int n, double* TP, double* TC, double* shd,
                       unsigned* cnt, int& bid){
  for (int k0 = 0; k0 < n; k0 += 64){
    int bs = n - k0; if (bs > 64) bs = 64;
    if (blockIdx.x == 0) gj_pivinv(A, n, n, k0, TP, shd);
    else gj_colcopy(A, n, n, k0, bs, TC);
    gbar(cnt, bid);
    gj_rowupd(A, n, n, k0, bs, TP, shd);
    gbar(cnt, bid);
    if (n - bs > 0){
      gj_mainupd(A, n, n, k0, bs, TC, shd);
      gbar(cnt, bid);
    }
  }
}

// ---------------- misc stages ----------------
__device__ void st_copy(const double* s, double* d, size_t n){
  for (size_t i = (size_t)blockIdx.x*TPB + threadIdx.x; i < n; i += (size_t)gridDim.x*TPB)
    d[i] = s[i];
}

__device__ void st_out(const double* Bg, float* out){
  int stride = gridDim.x*TPB;
  for (int idx = blockIdx.x*TPB + threadIdx.x; idx < 128*800; idx += stride){
    if (idx < 128*320){
      int t = idx/320, i = idx-(idx/320)*320;
      out[idx] = (float)Bg[(size_t)(480+i)*NBT + t];
    } else {
      int l = idx - 128*320;
      int t = l/480, i = l-(l/480)*480;
      out[idx] = (float)Bg[(size_t)i*NBT + t];
    }
  }
}

// ---------------- init kernel ----------------
__global__ __launch_bounds__(256) void k_init(unsigned* cnt){
  int i = blockIdx.x*256 + threadIdx.x;
  if (i < 1024) cnt[i] = 0;
}

// ---------------- mega kernel ----------------
__global__ __launch_bounds__(256) void k_mega(
    const float* Up, const float* Yp, const float* Uf, const float* Yf,
    const float* q, const float* r, const float* lam,
    const float* yref, const float* uref, const float* u_ini, const float* y_ini,
    float* out,
    double* Gram, double* M11, double* T12, double* G1, double* SP, double* R1,
    double* U1, double* X2b, double* Sm, double* dM, double* rhs2, double* tAc,
    double* P1, double* BUZ, double* TP, double* TC, unsigned* cnt){
  __shared__ double shd[4288];
  int bid = 0;
  double sg = 2.0*(double)lam[0];
  double isg = 1.0/sg, isg2 = isg*isg;

  // 1. Gram
  st_gram(Yf, Uf, Up, Yp, Gram, shd);
  gbar(cnt, bid);
  // 2. assembly
  st_assemble(Gram, q, r, isg, yref, uref, u_ini, y_ini, M11, T12, R1, dM, rhs2);
  gbar(cnt, bid);
  // 3. Ud = [B;P] @ dM -> R1 cols 400..527
  dgemm<0,1>(Gram, NQ, dM, NBT, R1+NC, NRHS, R1+NC, NRHS, KU, NBT, KB, 1.0, 0.0, shd);
  gbar(cnt, bid);
  // 4. M11 -> M11^{-1}
  gj_inv(M11, KB, TP, TC, shd, cnt, bid);
  // 5. G1 = M11i @ T12
  dgemm<0,0>(M11, KB, T12, KP, G1, KP, G1, KP, KB, KP, KB, 1.0, 0.0, shd);
  gbar(cnt, bid);
  // 6. SP = T12^T @ G1
  dgemm<1,0>(T12, KP, G1, KP, SP, KP, SP, KP, KP, KP, KB, 1.0, 0.0, shd);
  gbar(cnt, bid);
  // 7. SP -> SP^{-1}
  gj_inv(SP, KP, TP, TC, shd, cnt, bid);
  // 8. U1 = M11i @ R1top
  dgemm<0,0>(M11, KB, R1, NRHS, U1, NRHS, U1, NRHS, KB, NRHS, KB, 1.0, 0.0, shd);
  gbar(cnt, bid);
  // 9. V = T12^T @ U1 - R1low  (into R1low)
  dgemm<1,0>(T12, KP, U1, NRHS, R1+(size_t)KB*NRHS, NRHS, R1+(size_t)KB*NRHS, NRHS,
             KP, NRHS, KB, 1.0, -1.0, shd);
  gbar(cnt, bid);
  // 10. X2 = SPi @ V
  dgemm<0,0>(SP, KP, R1+(size_t)KB*NRHS, NRHS, X2b, NRHS, X2b, NRHS, KP, NRHS, KP, 1.0, 0.0, shd);
  gbar(cnt, bid);
  // 11. X1 = U1 - G1 @ X2 (into R1top); copy X2 -> R1low (independent regions)
  st_copy(X2b, R1+(size_t)KB*NRHS, (size_t)KP*NRHS);
  dgemm<0,0>(G1, KP, X2b, NRHS, U1, NRHS, R1, NRHS, KB, NRHS, KP, -1.0, 1.0, shd);
  gbar(cnt, bid);
  // 12. Sm = isg*AA^T - isg2*(J^T Z)
  dgemm<1,1>(Gram+800, NQ, R1, NRHS, Gram+(size_t)800*NQ+800, NQ, Sm, NC,
             NC, NC, KU, -isg2, isg, shd);
  gbar(cnt, bid);
  // 13. Sm -> Sm^{-1}
  gj_inv(Sm, NC, TP, TC, shd, cnt, bid);
  // 14. tAc = isg*(A B^T d) - b
  dgemm<0,0>(Gram+(size_t)800*NQ, NQ, dM, NBT, rhs2, NBT, tAc, NBT, NC, NBT, KB, isg, 1.0, shd);
  gbar(cnt, bid);
  // 15. rhs2 = tAc - isg2*(J^T Zc)
  dgemm<1,1>(Gram+800, NQ, R1+NC, NRHS, tAc, NBT, rhs2, NBT, NC, NBT, KU, -isg2, 1.0, shd);
  gbar(cnt, bid);
  // 16. nu = Smi @ rhs2 -> tAc
  dgemm<0,0>(Sm, NC, rhs2, NBT, tAc, NBT, tAc, NBT, NC, NBT, NC, 1.0, 0.0, shd);
  gbar(cnt, bid);
  // 17. P1 = isg*(BB^T d)
  dgemm<0,0>(Gram, NQ, dM, NBT, P1, NBT, P1, NBT, KB, NBT, KB, isg, 0.0, shd);
  gbar(cnt, bid);
  // 18. P1 -= isg*(BA^T nu)
  dgemm<0,0>(Gram+800, NQ, tAc, NBT, P1, NBT, P1, NBT, KB, NBT, NC, -isg, 1.0, shd);
  gbar(cnt, bid);
  // 19. P1 -= isg2*(BU Zc)
  dgemm<1,1>(Gram, NQ, R1+NC, NRHS, P1, NBT, P1, NBT, KB, NBT, KU, -isg2, 1.0, shd);
  gbar(cnt, bid);
  // 20. BUZ = BU @ Z
  dgemm<1,1>(Gram, NQ, R1, NRHS, BUZ, NC, BUZ, NC, KB, NC, KU, 1.0, 0.0, shd);
  gbar(cnt, bid);
  // 21. P1 += isg2*(BUZ nu)
  dgemm<0,0>(BUZ, NC, tAc, NBT, P1, NBT, P1, NBT, KB, NBT, NC, isg2, 1.0, shd);
  gbar(cnt, bid);
  // 22. output
  st_out(P1, out);
}

extern "C" void kernel_launch(void* const* d_in, const int* in_sizes, int n_in,
                              void* d_out, int out_size, void* d_ws, size_t ws_size,
                              hipStream_t stream){
  const float* Up   = (const float*)d_in[0];
  const float* Yp   = (const float*)d_in[1];
  const float* Uf   = (const float*)d_in[2];
  const float* Yf   = (const float*)d_in[3];
  // d_in[4] = IPI : unused (projector handled analytically)
  const float* q    = (const float*)d_in[5];
  const float* r    = (const float*)d_in[6];
  const float* lam  = (const float*)d_in[7];
  const float* yref = (const float*)d_in[8];
  const float* uref = (const float*)d_in[9];
  const float* u_ini= (const float*)d_in[10];
  const float* y_ini= (const float*)d_in[11];
  float* out = (float*)d_out;

  double* W = (double*)d_ws;
  size_t o = 0;
  double* Gram = W + o; o += (size_t)NQ*NQ;
  double* M11  = W + o; o += (size_t)KB*KB;
  double* T12  = W + o; o += (size_t)KB*KP;
  double* G1   = W + o; o += (size_t)KB*KP;
  double* SP   = W + o; o += (size_t)KP*KP;
  double* R1   = W + o; o += (size_t)KU*NRHS;
  double* U1   = W + o; o += (size_t)KB*NRHS;
  double* X2b  = W + o; o += (size_t)KP*NRHS;
  double* Sm   = W + o; o += (size_t)NC*NC;
  double* dM   = W + o; o += (size_t)KB*NBT;
  double* rhs2 = W + o; o += (size_t)NC*NBT;
  double* tAc  = W + o; o += (size_t)NC*NBT;
  double* P1   = W + o; o += (size_t)KB*NBT;
  double* BUZ  = W + o; o += (size_t)KB*NC;
  double* TP   = W + o; o += (size_t)64*64;
  double* TC   = W + o; o += (size_t)KB*64;
  unsigned* cnt = (unsigned*)(W + o); o += 512;
  if (ws_size < o*sizeof(double)) return;

  k_init<<<4,256,0,stream>>>(cnt);
  k_mega<<<GRID,TPB,0,stream>>>(Up,Yp,Uf,Yf,q,r,lam,yref,uref,u_ini,y_ini,out,
      Gram,M11,T12,G1,SP,R1,U1,X2b,Sm,dM,rhs2,tAc,P1,BUZ,TP,TC,cnt);
}

// Round 9
// 10188.468 us; speedup vs baseline: 2.8401x; 1.0603x over previous
//
#include <hip/hip_runtime.h>
#include <math.h>

#define NDIMX 2941
#define NQ 1200
#define KB 800
#define KP 720
#define KU 1520
#define NC 400
#define NBT 128
#define NRHS 528
#define GRID 256
#define TPB 256
#define PRLD 832

__device__ __forceinline__ int umap(int x){ return (x < 1200) ? x : x - 720; }

__device__ __forceinline__ const float* qrowp(int rr, const float* Yf, const float* Uf,
                                              const float* Up, const float* Yp){
  if (rr < 480) return Yf + (size_t)rr*NDIMX;
  if (rr < 800) return Uf + (size_t)(rr-480)*NDIMX;
  if (rr < 960) return Up + (size_t)(rr-800)*NDIMX;
  return Yp + (size_t)(rr-960)*NDIMX;
}

// ---------------- device-scope grid barrier (round-5 protocol, verified) ----------------
__device__ __forceinline__ void gbar(unsigned* cnt, int& id){
  __syncthreads();
  if (threadIdx.x == 0){
    unsigned* c = cnt + id;
    __hip_atomic_fetch_add(c, 1u, __ATOMIC_RELEASE, __HIP_MEMORY_SCOPE_SYSTEM);
    while (__hip_atomic_load(c, __ATOMIC_RELAXED, __HIP_MEMORY_SCOPE_SYSTEM) < (unsigned)GRID){
      __builtin_amdgcn_s_sleep(8);
    }
    (void)__hip_atomic_load(c, __ATOMIC_ACQUIRE, __HIP_MEMORY_SCOPE_AGENT);
  }
  __syncthreads();
  id++;
}

// XCD-aware bijective tile range (m204)
__device__ __forceinline__ void swz(int T, int& t0, int& tend){
  int x = blockIdx.x & 7, y = blockIdx.x >> 3;
  int q = T >> 3, r = T & 7;
  int nx = q + (x < r ? 1 : 0);
  int base = (x < r) ? x*(q+1) : r*(q+1) + (x-r)*q;
  t0 = base + y; tend = base + nx;
}

// ---------------- Gram stage (round-5 verified: f32 acc, f64 store) ----------------
__device__ void st_gram(const float* Yf, const float* Uf, const float* Up, const float* Yp,
                        double* G, double* shd){
  float* At = (float*)shd;          // [32][65]
  float* Bt = At + 32*65;           // [32][65]
  const int ntri = 190;
  int tid = threadIdx.x, tx = tid%16, ty = tid/16;
  int t0, tend; swz(ntri, t0, tend);
  for (int t = t0; t < tend; t += 32){
    int rem = t, ti = 0;
    while (rem >= ti+1){ rem -= ti+1; ++ti; }
    int tj = rem;
    int i0 = ti*64, j0 = tj*64;
    float acc[4][4] = {};
    for (int k0 = 0; k0 < NDIMX; k0 += 32){
      for (int l = tid; l < 2048; l += TPB){
        int r2 = l >> 5, k = l & 31;
        int gr = i0 + r2, gk = k0 + k;
        At[k*65 + r2] = (gr < NQ && gk < NDIMX) ? qrowp(gr,Yf,Uf,Up,Yp)[gk] : 0.f;
      }
      if (ti != tj){
        for (int l = tid; l < 2048; l += TPB){
          int r2 = l >> 5, k = l & 31;
          int gr = j0 + r2, gk = k0 + k;
          Bt[k*65 + r2] = (gr < NQ && gk < NDIMX) ? qrowp(gr,Yf,Uf,Up,Yp)[gk] : 0.f;
        }
      }
      __syncthreads();
      float* Bp = (ti==tj) ? At : Bt;
      #pragma unroll 8
      for (int kk=0; kk<32; ++kk){
        float a0=At[kk*65+ty*4+0],a1=At[kk*65+ty*4+1],a2=At[kk*65+ty*4+2],a3=At[kk*65+ty*4+3];
        float b0=Bp[kk*65+tx*4+0],b1=Bp[kk*65+tx*4+1],b2=Bp[kk*65+tx*4+2],b3=Bp[kk*65+tx*4+3];
        acc[0][0]+=a0*b0; acc[0][1]+=a0*b1; acc[0][2]+=a0*b2; acc[0][3]+=a0*b3;
        acc[1][0]+=a1*b0; acc[1][1]+=a1*b1; acc[1][2]+=a1*b2; acc[1][3]+=a1*b3;
        acc[2][0]+=a2*b0; acc[2][1]+=a2*b1; acc[2][2]+=a2*b2; acc[2][3]+=a2*b3;
        acc[3][0]+=a3*b0; acc[3][1]+=a3*b1; acc[3][2]+=a3*b2; acc[3][3]+=a3*b3;
      }
      __syncthreads();
    }
    for (int i=0;i<4;i++) for (int j=0;j<4;j++){
      int gi = i0 + ty*4 + i, gj = j0 + tx*4 + j;
      if (gi < NQ && gj < NQ){
        double v = (double)acc[i][j];
        G[(size_t)gi*NQ+gj] = v;
        G[(size_t)gj*NQ+gi] = v;
      }
    }
  }
}

// ---------------- fused elementwise assembly (round-5 verified) ----------------
__device__ void st_assemble(const double* G, const float* q, const float* r, double isg,
    const float* yref, const float* uref, const float* u_ini, const float* y_ini,
    double* M11, double* T12, double* R1, double* dM, double* rhs2){
  int tid0 = blockIdx.x*TPB + threadIdx.x, stride = gridDim.x*TPB;
  for (int idx=tid0; idx<KB*KB; idx+=stride){
    int i=idx/KB, j=idx-i*KB;
    double v = G[(size_t)i*NQ+j]*isg;
    if (i==j){ double w=(i<480)?(double)q[i%12]:(double)r[(i-480)%8]; v += 0.5/w; }
    M11[idx]=v;
  }
  for (int idx=tid0; idx<KB*KP; idx+=stride){
    int i=idx/KP, j=idx-i*KP;
    int pc=(j<400)?(800+j):(80+j);
    T12[idx]=G[(size_t)i*NQ+pc]*isg;
  }
  for (int idx=tid0; idx<KU*NC; idx+=stride){
    int i=idx/NC, j=idx-i*NC;
    R1[(size_t)i*NRHS+j]=G[(size_t)umap(i)*NQ+800+j];
  }
  for (int idx=tid0; idx<KB*NBT; idx+=stride){
    int k=idx/NBT, t=idx-k*NBT;
    dM[idx]=(k<480)? 2.0*(double)q[k%12]*(double)yref[(size_t)t*480+k]
                   : 2.0*(double)r[(k-480)%8]*(double)uref[(size_t)t*320+(k-480)];
  }
  for (int idx=tid0; idx<NC*NBT; idx+=stride){
    int j=idx/NBT, t=idx-j*NBT;
    rhs2[idx]= -((j<160)?(double)u_ini[(size_t)t*160+j]:(double)y_ini[(size_t)t*240+(j-160)]);
  }
}

// ---------------- f64 VALU GEMM (round-5 verified inner), swizzled tiles ----------------
template<int TRANSA, int MAPA>
__device__ void dgemm(const double* __restrict__ A, int lda, const double* __restrict__ B, int ldb,
    const double* __restrict__ Cin, int ldcin, double* __restrict__ Cout, int ldc,
    int M, int N, int K, double alpha, double beta, double* shd){
  double* As = shd;          // [16][66]
  double* Bs = shd + 1056;   // [16][66]
  int tid = threadIdx.x, tx = tid%16, ty = tid/16;
  int ntn = (N+63)>>6, ntm = (M+63)>>6;
  int t0, tend; swz(ntm*ntn, t0, tend);
  for (int t = t0; t < tend; t += 32){
    int m0 = (t/ntn)*64, n0 = (t%ntn)*64;
    double acc[4][4] = {};
    double ra[4], rb[4];
    auto loadAB = [&](int k0v){
      #pragma unroll
      for (int s=0;s<4;s++){
        int l = tid + s*TPB;
        if (TRANSA==0){
          int m = l>>4, k = l&15;
          int gm = m0+m, gk = k0v+k;
          double v = 0.0;
          if (gm<M && gk<K){ int row = MAPA ? umap(gm) : gm; v = A[(size_t)row*lda + gk]; }
          ra[s] = v;
        } else {
          int k = l>>6, m = l&63;
          int gm = m0+m, gk = k0v+k;
          double v = 0.0;
          if (gm<M && gk<K){ int row = MAPA ? umap(gk) : gk; v = A[(size_t)row*lda + gm]; }
          ra[s] = v;
        }
        int kb = l>>6, n = l&63;
        int gn = n0+n, gkb = k0v+kb;
        rb[s] = (gn<N && gkb<K) ? B[(size_t)gkb*ldb + gn] : 0.0;
      }
    };
    loadAB(0);
    for (int k0 = 0; k0 < K; k0 += 16){
      __syncthreads();
      #pragma unroll
      for (int s=0;s<4;s++){
        int l = tid + s*TPB;
        if (TRANSA==0){ int m=l>>4, k=l&15; As[k*66+m] = ra[s]; }
        else          { int k=l>>6, m=l&63; As[k*66+m] = ra[s]; }
        int kb=l>>6, n=l&63; Bs[kb*66+n] = rb[s];
      }
      __syncthreads();
      if (k0+16 < K) loadAB(k0+16);
      #pragma unroll
      for (int kk=0; kk<16; ++kk){
        double a0=As[kk*66+ty*4+0], a1=As[kk*66+ty*4+1], a2=As[kk*66+ty*4+2], a3=As[kk*66+ty*4+3];
        double b0=Bs[kk*66+tx*4+0], b1=Bs[kk*66+tx*4+1], b2=Bs[kk*66+tx*4+2], b3=Bs[kk*66+tx*4+3];
        acc[0][0]+=a0*b0; acc[0][1]+=a0*b1; acc[0][2]+=a0*b2; acc[0][3]+=a0*b3;
        acc[1][0]+=a1*b0; acc[1][1]+=a1*b1; acc[1][2]+=a1*b2; acc[1][3]+=a1*b3;
        acc[2][0]+=a2*b0; acc[2][1]+=a2*b1; acc[2][2]+=a2*b2; acc[2][3]+=a2*b3;
        acc[3][0]+=a3*b0; acc[3][1]+=a3*b1; acc[3][2]+=a3*b2; acc[3][3]+=a3*b3;
      }
      __syncthreads();
    }
    for (int i=0;i<4;i++) for (int j=0;j<4;j++){
      int gm = m0 + ty*4 + i, gn = n0 + tx*4 + j;
      if (gm < M && gn < N){
        double v = alpha*acc[i][j];
        if (beta != 0.0) v += beta*Cin[(size_t)gm*ldcin + gn];
        Cout[(size_t)gm*ldc + gn] = v;
      }
    }
  }
}

// ---------------- blocked Gauss-Jordan, 2 phases/panel (round-5 math) ----------------
__device__ void gj_pivinv(const double* A, int lda, int n, int k0, double* TP, double* shd){
  int bs = n - k0; if (bs > 64) bs = 64;
  double* sm = shd;            // [64][65]
  double* ck = shd + 64*65;
  double* rk = ck + 64;
  int tid = threadIdx.x;
  for (int l = tid; l < bs*bs; l += TPB){
    int i=l/bs, j=l-i*bs;
    sm[i*65+j] = A[(size_t)(k0+i)*lda + k0+j];
  }
  __syncthreads();
  for (int k=0;k<bs;k++){
    double d = 1.0/sm[k*65+k];
    if (tid < bs){ ck[tid] = sm[tid*65+k]; rk[tid] = (tid==k) ? d : sm[k*65+tid]*d; }
    __syncthreads();
    for (int l = tid; l < bs*bs; l += TPB){
      int i=l/bs, j=l-i*bs;
      double v;
      if (i==k) v = rk[j];
      else if (j==k) v = -ck[i]*d;
      else v = sm[i*65+j] - ck[i]*rk[j];
      sm[i*65+j] = v;
    }
    __syncthreads();
  }
  for (int l = tid; l < bs*bs; l += TPB){
    int i=l/bs, j=l-i*bs;
    TP[i*64+j] = sm[i*65+j];
  }
}

// Phase A (blocks != 0): TC = old pivot-column slab (outside rows),
// PR = old panel rows snapshot.
__device__ void gj_copies(const double* A, int lda, int n, int k0, int bs,
                          double* TC, double* PR){
  int nout = n - bs;
  int tot = nout*bs;
  for (int l = (blockIdx.x-1)*TPB + threadIdx.x; l < tot; l += (GRID-1)*TPB){
    int rr = l/bs, j = l - rr*bs;
    int i = (rr < k0) ? rr : rr + bs;
    TC[(size_t)rr*64 + j] = A[(size_t)i*lda + k0 + j];
  }
  int tot2 = bs*n;
  for (int l = (blockIdx.x-1)*TPB + threadIdx.x; l < tot2; l += (GRID-1)*TPB){
    int k = l/n, j = l - k*n;
    PR[(size_t)k*PRLD + j] = A[(size_t)(k0+k)*lda + j];
  }
}

// Phase B (fused rowupd+mainupd). FIX vs round 8: Pn's pivot-column range must
// hold TP (the updated panel content), not TP@PR (=I there). Pn now stores
// exactly what rowupd would write, so step 3's TC@Pn matches verified mainupd.
__device__ void gj_phaseB(double* A, int lda, int n, int k0, const double* TP,
                          const double* TC, const double* PR, double* shd){
  int bs = n - k0; if (bs > 64) bs = 64;
  int nout = n - bs;
  int ntc = (n+63)>>6, ntm = (nout+63)>>6;
  double* Pn = shd;               // [64][65]
  double* As = shd + 4160;        // [16][66]
  double* Bs = shd + 4160 + 1056; // [16][66]
  int tid = threadIdx.x, tx = tid%16, ty = tid/16;
  int T = ntm*ntc;
  for (int t = blockIdx.x; t < T; t += GRID){
    int mi = t / ntc, ci = t - mi*ntc;
    int m0 = mi*64, j0 = ci*64;
    // step 1: Pn = TP @ PR cols; pivot columns get TP directly
    double acc[4][4] = {};
    for (int kp=0; kp<bs; kp+=16){
      for (int l=tid; l<1024; l+=TPB){
        int k=l>>6, m=l&63;
        As[k*66+m] = (m<bs) ? TP[m*64 + kp+k] : 0.0;
      }
      for (int l=tid; l<1024; l+=TPB){
        int k=l>>6, j=l&63;
        Bs[k*66+j] = (j0+j<n) ? PR[(size_t)(kp+k)*PRLD + j0+j] : 0.0;
      }
      __syncthreads();
      #pragma unroll
      for (int kk=0; kk<16; ++kk){
        double a0=As[kk*66+ty*4+0], a1=As[kk*66+ty*4+1], a2=As[kk*66+ty*4+2], a3=As[kk*66+ty*4+3];
        double b0=Bs[kk*66+tx*4+0], b1=Bs[kk*66+tx*4+1], b2=Bs[kk*66+tx*4+2], b3=Bs[kk*66+tx*4+3];
        acc[0][0]+=a0*b0; acc[0][1]+=a0*b1; acc[0][2]+=a0*b2; acc[0][3]+=a0*b3;
        acc[1][0]+=a1*b0; acc[1][1]+=a1*b1; acc[1][2]+=a1*b2; acc[1][3]+=a1*b3;
        acc[2][0]+=a2*b0; acc[2][1]+=a2*b1; acc[2][2]+=a2*b2; acc[2][3]+=a2*b3;
        acc[3][0]+=a3*b0; acc[3][1]+=a3*b1; acc[3][2]+=a3*b2; acc[3][3]+=a3*b3;
      }
      __syncthreads();
    }
    for (int i=0;i<4;i++) for (int j=0;j<4;j++){
      int li = ty*4+i, lj = tx*4+j;
      int gj = j0 + lj;
      double v = acc[i][j];
      if (gj >= k0 && gj < k0+bs && li < bs) v = TP[li*64 + (gj-k0)];   // THE FIX
      Pn[li*65+lj] = v;
    }
    __syncthreads();
    // step 2: panel-row write duty (tile row 0 of each column strip)
    if (mi == 0){
      for (int l = tid; l < 64*64; l += TPB){
        int i2 = l>>6, j2 = l&63;
        int gj = j0 + j2;
        if (i2 < bs && gj < n) A[(size_t)(k0+i2)*lda + gj] = Pn[i2*65+j2];
      }
    }
    // step 3: outside-row update, B-operand = Pn (now correct at pivot cols)
    double acc2[4][4] = {};
    for (int kp=0; kp<bs; kp+=16){
      for (int l=tid; l<1024; l+=TPB){
        int k=l>>6, m=l&63;
        As[k*66+m] = (m0+m<nout) ? TC[(size_t)(m0+m)*64 + kp+k] : 0.0;
      }
      __syncthreads();
      #pragma unroll
      for (int kk=0; kk<16; ++kk){
        double a0=As[kk*66+ty*4+0], a1=As[kk*66+ty*4+1], a2=As[kk*66+ty*4+2], a3=As[kk*66+ty*4+3];
        double b0=Pn[(kp+kk)*65+tx*4+0], b1=Pn[(kp+kk)*65+tx*4+1],
               b2=Pn[(kp+kk)*65+tx*4+2], b3=Pn[(kp+kk)*65+tx*4+3];
        acc2[0][0]+=a0*b0; acc2[0][1]+=a0*b1; acc2[0][2]+=a0*b2; acc2[0][3]+=a0*b3;
        acc2[1][0]+=a1*b0; acc2[1][1]+=a1*b1; acc2[1][2]+=a1*b2; acc2[1][3]+=a1*b3;
        acc2[2][0]+=a2*b0; acc2[2][1]+=a2*b1; acc2[2][2]+=a2*b2; acc2[2][3]+=a2*b3;
        acc2[3][0]+=a3*b0; acc2[3][1]+=a3*b1; acc2[3][2]+=a3*b2; acc2[3][3]+=a3*b3;
      }
      __syncthreads();
    }
    for (int i=0;i<4;i++) for (int j=0;j<4;j++){
      int gm = m0 + ty*4 + i, gj = j0 + tx*4 + j;
      if (gm < nout && gj < n){
        int gi = (gm < k0) ? gm : gm + bs;
        double base = (gj >= k0 && gj < k0+bs) ? 0.0 : A[(size_t)gi*lda + gj];
        A[(size_t)gi*lda + gj] = base - acc2[i][j];
      }
    }
    __syncthreads();
  }
}

__device__ void gj_inv(double* A, int n, double* TP, double* TC, double* PR,
                       double* shd, unsigned* cnt, int& bid){
  for (int k0 = 0; k0 < n; k0 += 64){
    int bs = n - k0; if (bs > 64) bs = 64;
    if (blockIdx.x == 0) gj_pivinv(A, n, n, k0, TP, shd);
    else gj_copies(A, n, n, k0, bs, TC, PR);
    gbar(cnt, bid);
    gj_phaseB(A, n, n, k0, TP, TC, PR, shd);
    gbar(cnt, bid);
  }
}

// ---------------- misc stages ----------------
__device__ void st_copy(const double* s, double* d, size_t n){
  for (size_t i = (size_t)blockIdx.x*TPB + threadIdx.x; i < n; i += (size_t)gridDim.x*TPB)
    d[i] = s[i];
}

__device__ void st_out(const double* Bg, float* out){
  int stride = gridDim.x*TPB;
  for (int idx = blockIdx.x*TPB + threadIdx.x; idx < 128*800; idx += stride){
    if (idx < 128*320){
      int t = idx/320, i = idx-(idx/320)*320;
      out[idx] = (float)Bg[(size_t)(480+i)*NBT + t];
    } else {
      int l = idx - 128*320;
      int t = l/480, i = l-(l/480)*480;
      out[idx] = (float)Bg[(size_t)i*NBT + t];
    }
  }
}

__global__ __launch_bounds__(256) void k_init(unsigned* cnt){
  int i = blockIdx.x*256 + threadIdx.x;
  if (i < 1024) cnt[i] = 0;
}

// ---------------- mega kernel ----------------
__global__ __launch_bounds__(256) void k_mega(
    const float* Up, const float* Yp, const float* Uf, const float* Yf,
    const float* q, const float* r, const float* lam,
    const float* yref, const float* uref, const float* u_ini, const float* y_ini,
    float* out,
    double* Gram, double* M11, double* T12, double* G1, double* SP, double* R1,
    double* U1, double* X2b, double* Sm, double* dM, double* rhs2, double* tAc,
    double* P1, double* BUZ, double* TP, double* TC, double* PR, unsigned* cnt){
  __shared__ double shd[6272];
  int bid = 0;
  double sg = 2.0*(double)lam[0];
  double isg = 1.0/sg, isg2 = isg*isg;

  st_gram(Yf, Uf, Up, Yp, Gram, shd);
  gbar(cnt, bid);
  st_assemble(Gram, q, r, isg, yref, uref, u_ini, y_ini, M11, T12, R1, dM, rhs2);
  gbar(cnt, bid);
  // {3,14,17}
  dgemm<0,1>(Gram, NQ, dM, NBT, R1+NC, NRHS, R1+NC, NRHS, KU, NBT, KB, 1.0, 0.0, shd);
  dgemm<0,0>(Gram+(size_t)800*NQ, NQ, dM, NBT, rhs2, NBT, tAc, NBT, NC, NBT, KB, isg, 1.0, shd);
  dgemm<0,0>(Gram, NQ, dM, NBT, P1, NBT, P1, NBT, KB, NBT, KB, isg, 0.0, shd);
  gbar(cnt, bid);
  gj_inv(M11, KB, TP, TC, PR, shd, cnt, bid);
  // {5,8}
  dgemm<0,0>(M11, KB, T12, KP, G1, KP, G1, KP, KB, KP, KB, 1.0, 0.0, shd);
  dgemm<0,0>(M11, KB, R1, NRHS, U1, NRHS, U1, NRHS, KB, NRHS, KB, 1.0, 0.0, shd);
  gbar(cnt, bid);
  // {6,9}
  dgemm<1,0>(T12, KP, G1, KP, SP, KP, SP, KP, KP, KP, KB, 1.0, 0.0, shd);
  dgemm<1,0>(T12, KP, U1, NRHS, R1+(size_t)KB*NRHS, NRHS, R1+(size_t)KB*NRHS, NRHS,
             KP, NRHS, KB, 1.0, -1.0, shd);
  gbar(cnt, bid);
  gj_inv(SP, KP, TP, TC, PR, shd, cnt, bid);
  dgemm<0,0>(SP, KP, R1+(size_t)KB*NRHS, NRHS, X2b, NRHS, X2b, NRHS, KP, NRHS, KP, 1.0, 0.0, shd);
  gbar(cnt, bid);
  // {11}
  st_copy(X2b, R1+(size_t)KB*NRHS, (size_t)KP*NRHS);
  dgemm<0,0>(G1, KP, X2b, NRHS, U1, NRHS, R1, NRHS, KB, NRHS, KP, -1.0, 1.0, shd);
  gbar(cnt, bid);
  // {12,15,19,20}
  dgemm<1,1>(Gram+800, NQ, R1, NRHS, Gram+(size_t)800*NQ+800, NQ, Sm, NC,
             NC, NC, KU, -isg2, isg, shd);
  dgemm<1,1>(Gram+800, NQ, R1+NC, NRHS, tAc, NBT, rhs2, NBT, NC, NBT, KU, -isg2, 1.0, shd);
  dgemm<1,1>(Gram, NQ, R1+NC, NRHS, P1, NBT, P1, NBT, KB, NBT, KU, -isg2, 1.0, shd);
  dgemm<1,1>(Gram, NQ, R1, NRHS, BUZ, NC, BUZ, NC, KB, NC, KU, 1.0, 0.0, shd);
  gbar(cnt, bid);
  gj_inv(Sm, NC, TP, TC, PR, shd, cnt, bid);
  dgemm<0,0>(Sm, NC, rhs2, NBT, tAc, NBT, tAc, NBT, NC, NBT, NC, 1.0, 0.0, shd);
  gbar(cnt, bid);
  // {18,21}
  dgemm<0,0>(Gram+800, NQ, tAc, NBT, P1, NBT, P1, NBT, KB, NBT, NC, -isg, 1.0, shd);
  dgemm<0,0>(BUZ, NC, tAc, NBT, P1, NBT, P1, NBT, KB, NBT, NC, isg2, 1.0, shd);
  gbar(cnt, bid);
  st_out(P1, out);
}

extern "C" void kernel_launch(void* const* d_in, const int* in_sizes, int n_in,
                              void* d_out, int out_size, void* d_ws, size_t ws_size,
                              hipStream_t stream){
  const float* Up   = (const float*)d_in[0];
  const float* Yp   = (const float*)d_in[1];
  const float* Uf   = (const float*)d_in[2];
  const float* Yf   = (const float*)d_in[3];
  // d_in[4] = IPI : unused (projector handled analytically)
  const float* q    = (const float*)d_in[5];
  const float* r    = (const float*)d_in[6];
  const float* lam  = (const float*)d_in[7];
  const float* yref = (const float*)d_in[8];
  const float* uref = (const float*)d_in[9];
  const float* u_ini= (const float*)d_in[10];
  const float* y_ini= (const float*)d_in[11];
  float* out = (float*)d_out;

  double* W = (double*)d_ws;
  size_t o = 0;
  double* Gram = W + o; o += (size_t)NQ*NQ;
  double* M11  = W + o; o += (size_t)KB*KB;
  double* T12  = W + o; o += (size_t)KB*KP;
  double* G1   = W + o; o += (size_t)KB*KP;
  double* SP   = W + o; o += (size_t)KP*KP;
  double* R1   = W + o; o += (size_t)KU*NRHS;
  double* U1   = W + o; o += (size_t)KB*NRHS;
  double* X2b  = W + o; o += (size_t)KP*NRHS;
  double* Sm   = W + o; o += (size_t)NC*NC;
  double* dM   = W + o; o += (size_t)KB*NBT;
  double* rhs2 = W + o; o += (size_t)NC*NBT;
  double* tAc  = W + o; o += (size_t)NC*NBT;
  double* P1   = W + o; o += (size_t)KB*NBT;
  double* BUZ  = W + o; o += (size_t)KB*NC;
  double* TP   = W + o; o += (size_t)64*64;
  double* TC   = W + o; o += (size_t)KB*64;
  double* PR   = W + o; o += (size_t)64*PRLD;
  unsigned* cnt = (unsigned*)(W + o); o += 512;
  if (ws_size < o*sizeof(double)) return;

  k_init<<<4,256,0,stream>>>(cnt);
  k_mega<<<GRID,TPB,0,stream>>>(Up,Yp,Uf,Yf,q,r,lam,yref,uref,u_ini,y_ini,out,
      Gram,M11,T12,G1,SP,R1,U1,X2b,Sm,dM,rhs2,tAc,P1,BUZ,TP,TC,PR,cnt);
}